// Round 1
// baseline (1768.449 us; speedup 1.0000x reference)
//
#include <hip/hip_runtime.h>
#include <cstdint>
#include <cstddef>

#define INORM_EPS 1e-5f

// ---------------- per-(b,c) mean / rstd over spatial dims ----------------
__global__ __launch_bounds__(256) void stats_kernel(
    const float* __restrict__ in, float2* __restrict__ stats, int HW) {
  const size_t map = blockIdx.x;
  const float* p = in + map * (size_t)HW;
  float s = 0.f, ss = 0.f;
  for (int i = threadIdx.x; i < HW; i += 256) {
    float v = p[i];
    s += v;
    ss += v * v;
  }
  __shared__ float r0[256], r1[256];
  r0[threadIdx.x] = s;
  r1[threadIdx.x] = ss;
  __syncthreads();
  for (int off = 128; off > 0; off >>= 1) {
    if ((int)threadIdx.x < off) {
      r0[threadIdx.x] += r0[threadIdx.x + off];
      r1[threadIdx.x] += r1[threadIdx.x + off];
    }
    __syncthreads();
  }
  if (threadIdx.x == 0) {
    float mean = r0[0] / (float)HW;
    float var = r1[0] / (float)HW - mean * mean;
    stats[map] = make_float2(mean, rsqrtf(var + INORM_EPS));
  }
}

// ---------------- 3x3 conv, 32->32, fused instnorm+relu on input --------
// Thread map: tid = x(8) | y(8) | coutgrp(4).  Each wave has a uniform
// cout-group -> weight LDS reads are broadcasts.  YPT = output rows/thread.
template <int STRIDE, int YPT>
__global__ __launch_bounds__(256) void conv3x3_kernel(
    const float* __restrict__ in, int Hin, int Win,
    const float2* __restrict__ stats,           // [b*32]
    const float* __restrict__ w,                // [32][32][3][3]
    const float* __restrict__ bias,             // [32]
    const float* __restrict__ skip,             // identity skip (out shape) or null
    float* __restrict__ out, int Hout, int Wout) {
  constexpr int TW_OUT = 8, TH_OUT = 8 * YPT;
  constexpr int TW_IN = (TW_OUT - 1) * STRIDE + 3;
  constexpr int TH_IN = (TH_OUT - 1) * STRIDE + 3;
  __shared__ __align__(16) float s_w[32 * 9 * 32];  // [(ci*9+k)*32 + co]
  __shared__ float s_in[32 * TH_IN * TW_IN];

  const int t = threadIdx.x;
  const int b = blockIdx.z;
  const int x0 = blockIdx.x * TW_OUT;
  const int y0 = blockIdx.y * TH_OUT;

  // stage weights, transposed so 8 consecutive couts are contiguous
  for (int d = t; d < 32 * 32 * 9; d += 256) {
    int co = d & 31;
    int rest = d >> 5;
    int k = rest % 9;
    int ci = rest / 9;
    s_w[d] = w[co * 288 + ci * 9 + k];
  }
  // stage input tile, normalized + relu on the fly
  const int xi0 = x0 * STRIDE - 1;
  const int yi0 = y0 * STRIDE - 1;
  for (int d = t; d < 32 * TH_IN * TW_IN; d += 256) {
    int ci = d / (TH_IN * TW_IN);
    int r = d - ci * TH_IN * TW_IN;
    int yy = r / TW_IN;
    int xx = r - yy * TW_IN;
    int gy = yi0 + yy, gx = xi0 + xx;
    float v = 0.f;
    if (gy >= 0 && gy < Hin && gx >= 0 && gx < Win) {
      float2 st = stats[b * 32 + ci];
      float raw = in[(((size_t)b * 32 + ci) * Hin + gy) * Win + gx];
      v = fmaxf(0.f, (raw - st.x) * st.y);
    }
    s_in[d] = v;
  }
  __syncthreads();

  const int xo = t & 7;
  const int yo = (t >> 3) & 7;
  const int co0 = (t >> 6) * 8;
  float acc[YPT][8];
#pragma unroll
  for (int j = 0; j < YPT; j++)
#pragma unroll
    for (int c = 0; c < 8; c++) acc[j][c] = 0.f;

  for (int ci = 0; ci < 32; ci++) {
    const float* sin = &s_in[ci * TH_IN * TW_IN];
    const float* sw = &s_w[ci * 288 + co0];
#pragma unroll
    for (int ky = 0; ky < 3; ky++) {
#pragma unroll
      for (int kx = 0; kx < 3; kx++) {
        const int k = ky * 3 + kx;
        float4 wa = *(const float4*)&sw[k * 32];
        float4 wb = *(const float4*)&sw[k * 32 + 4];
#pragma unroll
        for (int j = 0; j < YPT; j++) {
          float iv = sin[((yo + j * 8) * STRIDE + ky) * TW_IN + xo * STRIDE + kx];
          acc[j][0] += iv * wa.x;
          acc[j][1] += iv * wa.y;
          acc[j][2] += iv * wa.z;
          acc[j][3] += iv * wa.w;
          acc[j][4] += iv * wb.x;
          acc[j][5] += iv * wb.y;
          acc[j][6] += iv * wb.z;
          acc[j][7] += iv * wb.w;
        }
      }
    }
  }
#pragma unroll
  for (int j = 0; j < YPT; j++) {
    int oy = y0 + yo + j * 8;
#pragma unroll
    for (int c = 0; c < 8; c++) {
      int co = co0 + c;
      size_t idx = (((size_t)b * 32 + co) * Hout + oy) * Wout + x0 + xo;
      float v = acc[j][c] + bias[co];
      if (skip) v += skip[idx];
      out[idx] = v;
    }
  }
}

// ---------------- 7x7 s2 conv, 3->32, fused instnorm (no relu) ----------
__global__ __launch_bounds__(256) void conv7_kernel(
    const float* __restrict__ in,       // [64][3][256][256]
    const float2* __restrict__ stats,   // [64*3]
    const float* __restrict__ w,        // [32][3][7][7]
    const float* __restrict__ bias,     // [32]
    float* __restrict__ out) {          // [64][32][128][128]
  constexpr int TW_OUT = 8, TH_OUT = 16;
  constexpr int TW_IN = (TW_OUT - 1) * 2 + 7;  // 21
  constexpr int TH_IN = (TH_OUT - 1) * 2 + 7;  // 37
  __shared__ __align__(16) float s_w[3 * 49 * 32];  // [(ci*49+k)*32 + co]
  __shared__ float s_in[3 * TH_IN * TW_IN];

  const int t = threadIdx.x;
  const int b = blockIdx.z;
  const int x0 = blockIdx.x * TW_OUT;
  const int y0 = blockIdx.y * TH_OUT;

  for (int d = t; d < 3 * 49 * 32; d += 256) {
    int co = d & 31;
    int rest = d >> 5;
    int k = rest % 49;
    int ci = rest / 49;
    s_w[d] = w[co * 147 + ci * 49 + k];
  }
  const int xi0 = x0 * 2 - 3;
  const int yi0 = y0 * 2 - 3;
  for (int d = t; d < 3 * TH_IN * TW_IN; d += 256) {
    int ci = d / (TH_IN * TW_IN);
    int r = d - ci * TH_IN * TW_IN;
    int yy = r / TW_IN;
    int xx = r - yy * TW_IN;
    int gy = yi0 + yy, gx = xi0 + xx;
    float v = 0.f;
    if (gy >= 0 && gy < 256 && gx >= 0 && gx < 256) {
      float2 st = stats[b * 3 + ci];
      v = (in[(((size_t)b * 3 + ci) * 256 + gy) * 256 + gx] - st.x) * st.y;
    }
    s_in[d] = v;
  }
  __syncthreads();

  const int xo = t & 7;
  const int yo = (t >> 3) & 7;
  const int co0 = (t >> 6) * 8;
  float acc[2][8];
#pragma unroll
  for (int j = 0; j < 2; j++)
#pragma unroll
    for (int c = 0; c < 8; c++) acc[j][c] = 0.f;

  for (int ci = 0; ci < 3; ci++) {
    const float* sin = &s_in[ci * TH_IN * TW_IN];
    const float* sw = &s_w[ci * 49 * 32 + co0];
    for (int ky = 0; ky < 7; ky++) {
#pragma unroll
      for (int kx = 0; kx < 7; kx++) {
        const int k = ky * 7 + kx;
        float4 wa = *(const float4*)&sw[k * 32];
        float4 wb = *(const float4*)&sw[k * 32 + 4];
#pragma unroll
        for (int j = 0; j < 2; j++) {
          float iv = sin[((yo + j * 8) * 2 + ky) * TW_IN + xo * 2 + kx];
          acc[j][0] += iv * wa.x;
          acc[j][1] += iv * wa.y;
          acc[j][2] += iv * wa.z;
          acc[j][3] += iv * wa.w;
          acc[j][4] += iv * wb.x;
          acc[j][5] += iv * wb.y;
          acc[j][6] += iv * wb.z;
          acc[j][7] += iv * wb.w;
        }
      }
    }
  }
#pragma unroll
  for (int j = 0; j < 2; j++) {
    int oy = y0 + yo + j * 8;
#pragma unroll
    for (int c = 0; c < 8; c++) {
      int co = co0 + c;
      size_t idx = (((size_t)b * 32 + co) * 128 + oy) * 128 + x0 + xo;
      out[idx] = acc[j][c] + bias[co];
    }
  }
}

// ---------------- 1x1 stride-2 skip projection, accumulate into out ------
__global__ __launch_bounds__(256) void conv1x1s2_accum_kernel(
    const float* __restrict__ in, int Hin, int Win,
    const float* __restrict__ w,    // [32][32]
    const float* __restrict__ bs,   // [32]
    float* __restrict__ out, int Hout, int Wout) {
  size_t idx = (size_t)blockIdx.x * 256 + threadIdx.x;
  int ox = idx % Wout;
  size_t r = idx / Wout;
  int oy = r % Hout;
  r /= Hout;
  int co = r & 31;
  int b = r >> 5;
  const float* ip = in + (((size_t)b * 32) * Hin + oy * 2) * Win + ox * 2;
  const float* wp = w + co * 32;
  float acc = bs[co];
#pragma unroll 8
  for (int ci = 0; ci < 32; ci++) acc += wp[ci] * ip[(size_t)ci * Hin * Win];
  out[idx] += acc;
}

// ---------------- fused attention tail: one block per batch sample -------
__global__ __launch_bounds__(256) void attention_kernel(
    const float* __restrict__ feat,     // [64][32][16][16]
    const float* __restrict__ text,     // [64][256]
    const float* __restrict__ attn_w,   // [5][256][256]
    const float* __restrict__ attn_b,   // [5][256]
    const float* __restrict__ final_w,  // [512][1280]
    const float* __restrict__ final_b,  // [512]
    float* __restrict__ out) {          // [64][512]
  __shared__ float s_text[256];
  __shared__ float s_feat[32 * 256];
  __shared__ float s_gate[5 * 256];
  __shared__ float s_scores[5 * 32];
  __shared__ float s_probs[5 * 32];
  __shared__ float s_amap[5 * 256];
  const int b = blockIdx.x;
  const int t = threadIdx.x;

  s_text[t] = text[b * 256 + t];
  for (int i = t; i < 32 * 256; i += 256) s_feat[i] = feat[(size_t)b * 8192 + i];
  __syncthreads();

  // gates: sigmoid(text . attn_w[h][o] + attn_b[h][o]), o == t
  for (int h = 0; h < 5; h++) {
    const float* wrow = attn_w + ((size_t)h * 256 + t) * 256;
    float acc = attn_b[h * 256 + t];
    for (int k = 0; k < 256; k++) acc += s_text[k] * wrow[k];
    s_gate[h * 256 + t] = 1.f / (1.f + __expf(-acc));
  }
  __syncthreads();

  // scores[h][c] = sum_ij gate[h][ij] * feat[c][ij]
  if (t < 160) {
    int h = t >> 5, c = t & 31;
    float acc = 0.f;
    for (int ij = 0; ij < 256; ij++) acc += s_gate[h * 256 + ij] * s_feat[c * 256 + ij];
    s_scores[t] = acc;
  }
  __syncthreads();

  // softmax over c (32) per head
  if (t < 5) {
    float mx = -1e30f;
    for (int c = 0; c < 32; c++) mx = fmaxf(mx, s_scores[t * 32 + c]);
    float sum = 0.f;
    for (int c = 0; c < 32; c++) {
      float e = __expf(s_scores[t * 32 + c] - mx);
      s_probs[t * 32 + c] = e;
      sum += e;
    }
    float inv = 1.f / sum;
    for (int c = 0; c < 32; c++) s_probs[t * 32 + c] *= inv;
  }
  __syncthreads();

  // amaps[h][ij] = sum_c probs[h][c] * feat[c][ij], ij == t
  for (int h = 0; h < 5; h++) {
    float acc = 0.f;
    for (int c = 0; c < 32; c++) acc += s_probs[h * 32 + c] * s_feat[c * 256 + t];
    s_amap[h * 256 + t] = acc;
  }
  __syncthreads();

  // final linear: out[b][e] = amap . final_w[e] + final_b[e]
  for (int e = t; e < 512; e += 256) {
    const float* wrow = final_w + (size_t)e * 1280;
    float acc = final_b[e];
    for (int k = 0; k < 1280; k++) acc += s_amap[k] * wrow[k];
    out[(size_t)b * 512 + e] = acc;
  }
}

// -------------------------------------------------------------------------
extern "C" void kernel_launch(void* const* d_in, const int* in_sizes, int n_in,
                              void* d_out, int out_size, void* d_ws, size_t ws_size,
                              hipStream_t stream) {
  (void)in_sizes; (void)n_in; (void)out_size; (void)ws_size;
  const float* x       = (const float*)d_in[0];
  const float* text    = (const float*)d_in[1];
  const float* conv1_w = (const float*)d_in[2];
  const float* conv1_b = (const float*)d_in[3];
  const float* rbs_w1  = (const float*)d_in[4];
  const float* rbs_b1  = (const float*)d_in[5];
  const float* rbs_w2  = (const float*)d_in[6];
  const float* rbs_b2  = (const float*)d_in[7];
  const float* rbs_ws  = (const float*)d_in[8];
  const float* rbs_bs  = (const float*)d_in[9];
  const float* rb_w1   = (const float*)d_in[10];
  const float* rb_b1   = (const float*)d_in[11];
  const float* rb_w2   = (const float*)d_in[12];
  const float* rb_b2   = (const float*)d_in[13];
  const float* attn_w  = (const float*)d_in[14];
  const float* attn_b  = (const float*)d_in[15];
  const float* final_w = (const float*)d_in[16];
  const float* final_b = (const float*)d_in[17];
  float* out = (float*)d_out;

  char* wsb = (char*)d_ws;
  float* A  = (float*)wsb;                                     // 64*32*128*128 f = 134217728 B
  float* Bu = (float*)(wsb + 134217728);                       // 64*32*64*64 f = 33554432 B
  float* Cu = (float*)(wsb + 134217728 + 33554432);
  float* Du = (float*)(wsb + 134217728 + 2 * 33554432);
  float2* S0 = (float2*)(wsb + 134217728 + 3 * 33554432);      // 2048 float2
  float2* S1 = S0 + 2048;

  // stage 0: instnorm(x) fused into conv1 (7x7 s2 p3, 3->32): 256^2 -> 128^2
  stats_kernel<<<192, 256, 0, stream>>>(x, S0, 256 * 256);
  conv7_kernel<<<dim3(16, 8, 64), 256, 0, stream>>>(x, S0, conv1_w, conv1_b, A);

  // rbs0: 128^2 -> 64^2   (A -> Bu -> Cu; skip 1x1(A) += Cu)
  stats_kernel<<<2048, 256, 0, stream>>>(A, S0, 128 * 128);
  conv3x3_kernel<2, 1><<<dim3(8, 8, 64), 256, 0, stream>>>(
      A, 128, 128, S0, rbs_w1, rbs_b1, nullptr, Bu, 64, 64);
  stats_kernel<<<2048, 256, 0, stream>>>(Bu, S1, 64 * 64);
  conv3x3_kernel<1, 2><<<dim3(8, 4, 64), 256, 0, stream>>>(
      Bu, 64, 64, S1, rbs_w2, rbs_b2, nullptr, Cu, 64, 64);
  conv1x1s2_accum_kernel<<<(64 * 32 * 64 * 64) / 256, 256, 0, stream>>>(
      A, 128, 128, rbs_ws, rbs_bs, Cu, 64, 64);

  // rb0: 64^2   (Cu -> Bu -> Du, +Cu identity)
  stats_kernel<<<2048, 256, 0, stream>>>(Cu, S0, 64 * 64);
  conv3x3_kernel<1, 2><<<dim3(8, 4, 64), 256, 0, stream>>>(
      Cu, 64, 64, S0, rb_w1, rb_b1, nullptr, Bu, 64, 64);
  stats_kernel<<<2048, 256, 0, stream>>>(Bu, S1, 64 * 64);
  conv3x3_kernel<1, 2><<<dim3(8, 4, 64), 256, 0, stream>>>(
      Bu, 64, 64, S1, rb_w2, rb_b2, Cu, Du, 64, 64);

  // rbs1: 64^2 -> 32^2  (Du -> Bu -> Cu; skip 1x1(Du) += Cu)
  stats_kernel<<<2048, 256, 0, stream>>>(Du, S0, 64 * 64);
  conv3x3_kernel<2, 1><<<dim3(4, 4, 64), 256, 0, stream>>>(
      Du, 64, 64, S0, rbs_w1 + 9216, rbs_b1 + 32, nullptr, Bu, 32, 32);
  stats_kernel<<<2048, 256, 0, stream>>>(Bu, S1, 32 * 32);
  conv3x3_kernel<1, 2><<<dim3(4, 2, 64), 256, 0, stream>>>(
      Bu, 32, 32, S1, rbs_w2 + 9216, rbs_b2 + 32, nullptr, Cu, 32, 32);
  conv1x1s2_accum_kernel<<<(64 * 32 * 32 * 32) / 256, 256, 0, stream>>>(
      Du, 64, 64, rbs_ws + 1024, rbs_bs + 32, Cu, 32, 32);

  // rb1: 32^2   (Cu -> Bu -> Du, +Cu identity)
  stats_kernel<<<2048, 256, 0, stream>>>(Cu, S0, 32 * 32);
  conv3x3_kernel<1, 2><<<dim3(4, 2, 64), 256, 0, stream>>>(
      Cu, 32, 32, S0, rb_w1 + 9216, rb_b1 + 32, nullptr, Bu, 32, 32);
  stats_kernel<<<2048, 256, 0, stream>>>(Bu, S1, 32 * 32);
  conv3x3_kernel<1, 2><<<dim3(4, 2, 64), 256, 0, stream>>>(
      Bu, 32, 32, S1, rb_w2 + 9216, rb_b2 + 32, Cu, Du, 32, 32);

  // rbs2: 32^2 -> 16^2  (Du -> Bu -> Cu; skip 1x1(Du) += Cu)
  stats_kernel<<<2048, 256, 0, stream>>>(Du, S0, 32 * 32);
  conv3x3_kernel<2, 1><<<dim3(2, 2, 64), 256, 0, stream>>>(
      Du, 32, 32, S0, rbs_w1 + 2 * 9216, rbs_b1 + 64, nullptr, Bu, 16, 16);
  stats_kernel<<<2048, 256, 0, stream>>>(Bu, S1, 16 * 16);
  conv3x3_kernel<1, 2><<<dim3(2, 1, 64), 256, 0, stream>>>(
      Bu, 16, 16, S1, rbs_w2 + 2 * 9216, rbs_b2 + 64, nullptr, Cu, 16, 16);
  conv1x1s2_accum_kernel<<<(64 * 32 * 16 * 16) / 256, 256, 0, stream>>>(
      Du, 32, 32, rbs_ws + 2048, rbs_bs + 64, Cu, 16, 16);

  // attention tail
  attention_kernel<<<64, 256, 0, stream>>>(
      Cu, text, attn_w, attn_b, final_w, final_b, out);
}

// Round 2
// 1495.816 us; speedup vs baseline: 1.1823x; 1.1823x over previous
//
#include <hip/hip_runtime.h>
#include <cstdint>
#include <cstddef>

#define INORM_EPS 1e-5f

// ---------------- zero the stats accumulation pool ----------------------
__global__ __launch_bounds__(256) void zero_f2(float2* __restrict__ p, int n) {
  int i = blockIdx.x * 256 + threadIdx.x;
  if (i < n) p[i] = make_float2(0.f, 0.f);
}

// ---- weight transpose: [co][ci][3][3] -> [(ci*9+k)*32+co], nmat mats ----
__global__ __launch_bounds__(256) void transpose_w3(const float* __restrict__ src,
                                                    float* __restrict__ dst, int nmat) {
  int d = blockIdx.x * 256 + threadIdx.x;
  if (d >= nmat * 9216) return;
  int mat = d / 9216, r = d % 9216;
  int co = r & 31, t2 = r >> 5;
  int k = t2 % 9, ci = t2 / 9;
  dst[d] = src[mat * 9216 + co * 288 + ci * 9 + k];
}
// ---- conv1 weights: [co][ci][7][7] -> [(ci*49+k)*32+co] ----------------
__global__ __launch_bounds__(256) void transpose_w7(const float* __restrict__ src,
                                                    float* __restrict__ dst) {
  int d = blockIdx.x * 256 + threadIdx.x;
  if (d >= 4704) return;
  int co = d & 31, t2 = d >> 5;
  int k = t2 % 49, ci = t2 / 49;
  dst[d] = src[co * 147 + ci * 49 + k];
}

// ---------------- raw (sum, sumsq) stats for the input x ----------------
__global__ __launch_bounds__(256) void stats_raw(const float* __restrict__ in,
                                                 float2* __restrict__ st, int HW) {
  const float4* p = (const float4*)(in + (size_t)blockIdx.x * HW);
  float s = 0.f, ss = 0.f;
  int n4 = HW >> 2;
  for (int i = threadIdx.x; i < n4; i += 256) {
    float4 v = p[i];
    s += v.x + v.y + v.z + v.w;
    ss += v.x * v.x + v.y * v.y + v.z * v.z + v.w * v.w;
  }
  __shared__ float r0[256], r1[256];
  r0[threadIdx.x] = s;
  r1[threadIdx.x] = ss;
  __syncthreads();
  for (int off = 128; off > 0; off >>= 1) {
    if ((int)threadIdx.x < off) {
      r0[threadIdx.x] += r0[threadIdx.x + off];
      r1[threadIdx.x] += r1[threadIdx.x + off];
    }
    __syncthreads();
  }
  if (threadIdx.x == 0) st[blockIdx.x] = make_float2(r0[0], r1[0]);
}

// ---------------- 3x3 stride-1 conv, 32->32, square map W x W -----------
// lane = x + W*s (row-slice), 4 waves = 4 cout-groups of 8.
// Each thread: RPT rows (r = s + SL*i), 8 couts, register iv column reuse.
template <int W, int SL, int RPT>
__global__ __launch_bounds__(256) void conv3x3_s1(
    const float* __restrict__ in, const float2* __restrict__ stats, float inv_hw,
    const float* __restrict__ wT, const float* __restrict__ bias,
    const float* __restrict__ skip, float* __restrict__ out,
    float2* __restrict__ ostats) {
  constexpr int RPB = SL * RPT;
  constexpr int ROWS = RPB + 2;
  constexpr int WS = W + 2;
  constexpr int NIV = SL * (RPT - 1) + 3;
  __shared__ float s_in[8 * ROWS * WS];
  __shared__ __align__(16) float s_w[8 * 9 * 32];
  __shared__ float2 s_ms[8];
  const int t = threadIdx.x;
  const int b = blockIdx.z;
  const int y0 = blockIdx.x * RPB;
  const int lane = t & 63, wv = t >> 6;
  const int x = lane % W, s = lane / W;
  const int co0 = wv * 8;

  float acc[RPT][8];
#pragma unroll
  for (int i = 0; i < RPT; i++)
#pragma unroll
    for (int c = 0; c < 8; c++) acc[i][c] = 0.f;

  for (int c0 = 0; c0 < 32; c0 += 8) {
    if (c0) __syncthreads();
    if (t < 8) {
      float2 r = stats[b * 32 + c0 + t];
      float mean = r.x * inv_hw;
      float var = r.y * inv_hw - mean * mean;
      s_ms[t] = make_float2(mean, rsqrtf(var + INORM_EPS));
    }
    __syncthreads();
    for (int d = t; d < 8 * 9 * 32; d += 256) s_w[d] = wT[c0 * 288 + d];
    for (int d = t; d < 8 * ROWS * WS; d += 256) {
      int ci = d / (ROWS * WS);
      int r = d % (ROWS * WS);
      int lr = r / WS, cc = r % WS;
      int gy = y0 - 1 + lr, gx = cc - 1;
      float v = 0.f;
      if ((unsigned)gy < (unsigned)W && (unsigned)gx < (unsigned)W) {
        float2 ms = s_ms[ci];
        float raw = in[(((size_t)b * 32 + c0 + ci) * W + gy) * W + gx];
        v = fmaxf(0.f, (raw - ms.x) * ms.y);
      }
      s_in[d] = v;
    }
    __syncthreads();

    for (int ci = 0; ci < 8; ci++) {
      const float* sci = &s_in[ci * ROWS * WS];
      const float* swc = &s_w[ci * 288 + co0];
      for (int kx = 0; kx < 3; kx++) {
        float ivv[NIV];
#pragma unroll
        for (int v = 0; v < NIV; v++) ivv[v] = sci[(s + v) * WS + x + kx];
#pragma unroll
        for (int ky = 0; ky < 3; ky++) {
          const float4 wa = *(const float4*)&swc[(ky * 3 + kx) * 32];
          const float4 wb = *(const float4*)&swc[(ky * 3 + kx) * 32 + 4];
#pragma unroll
          for (int i = 0; i < RPT; i++) {
            float iv = ivv[SL * i + ky];
            acc[i][0] = fmaf(iv, wa.x, acc[i][0]);
            acc[i][1] = fmaf(iv, wa.y, acc[i][1]);
            acc[i][2] = fmaf(iv, wa.z, acc[i][2]);
            acc[i][3] = fmaf(iv, wa.w, acc[i][3]);
            acc[i][4] = fmaf(iv, wb.x, acc[i][4]);
            acc[i][5] = fmaf(iv, wb.y, acc[i][5]);
            acc[i][6] = fmaf(iv, wb.z, acc[i][6]);
            acc[i][7] = fmaf(iv, wb.w, acc[i][7]);
          }
        }
      }
    }
  }

  float sm[8], sq[8];
#pragma unroll
  for (int c = 0; c < 8; c++) { sm[c] = 0.f; sq[c] = 0.f; }
#pragma unroll
  for (int i = 0; i < RPT; i++) {
    int gy = y0 + s + SL * i;
#pragma unroll
    for (int c = 0; c < 8; c++) {
      int co = co0 + c;
      float v = acc[i][c] + bias[co];
      size_t idx = (((size_t)b * 32 + co) * W + gy) * W + x;
      if (skip) v += skip[idx];
      out[idx] = v;
      sm[c] += v;
      sq[c] += v * v;
    }
  }
  if (ostats) {
#pragma unroll
    for (int c = 0; c < 8; c++) {
      float a = sm[c], q = sq[c];
      for (int off = 32; off > 0; off >>= 1) {
        a += __shfl_down(a, off);
        q += __shfl_down(q, off);
      }
      if (lane == 0) {
        atomicAdd(&ostats[b * 32 + co0 + c].x, a);
        atomicAdd(&ostats[b * 32 + co0 + c].y, q);
      }
    }
  }
}

// ---------------- 3x3 stride-2 conv, 32->32, in 2W -> out W -------------
template <int WO, int SL, int RPT>
__global__ __launch_bounds__(256) void conv3x3_s2(
    const float* __restrict__ in, const float2* __restrict__ stats, float inv_hw,
    const float* __restrict__ wT, const float* __restrict__ bias,
    float* __restrict__ out, float2* __restrict__ ostats) {
  constexpr int RPB = SL * RPT;
  constexpr int ROWS = 2 * RPB + 1;
  constexpr int WIN = 2 * WO;
  constexpr int WS = WIN + 2;
  __shared__ float s_in[8 * ROWS * WS];
  __shared__ __align__(16) float s_w[8 * 9 * 32];
  __shared__ float2 s_ms[8];
  const int t = threadIdx.x;
  const int b = blockIdx.z;
  const int y0 = blockIdx.x * RPB;
  const int lane = t & 63, wv = t >> 6;
  const int x = lane % WO, s = lane / WO;
  const int co0 = wv * 8;

  float acc[RPT][8];
#pragma unroll
  for (int i = 0; i < RPT; i++)
#pragma unroll
    for (int c = 0; c < 8; c++) acc[i][c] = 0.f;

  for (int c0 = 0; c0 < 32; c0 += 8) {
    if (c0) __syncthreads();
    if (t < 8) {
      float2 r = stats[b * 32 + c0 + t];
      float mean = r.x * inv_hw;
      float var = r.y * inv_hw - mean * mean;
      s_ms[t] = make_float2(mean, rsqrtf(var + INORM_EPS));
    }
    __syncthreads();
    for (int d = t; d < 8 * 9 * 32; d += 256) s_w[d] = wT[c0 * 288 + d];
    for (int d = t; d < 8 * ROWS * WS; d += 256) {
      int ci = d / (ROWS * WS);
      int r = d % (ROWS * WS);
      int lr = r / WS, cc = r % WS;
      int gy = 2 * y0 - 1 + lr, gx = cc - 1;
      float v = 0.f;
      if ((unsigned)gy < (unsigned)WIN && (unsigned)gx < (unsigned)WIN) {
        float2 ms = s_ms[ci];
        float raw = in[(((size_t)b * 32 + c0 + ci) * WIN + gy) * WIN + gx];
        v = fmaxf(0.f, (raw - ms.x) * ms.y);
      }
      s_in[d] = v;
    }
    __syncthreads();

    for (int ci = 0; ci < 8; ci++) {
      const float* sci = &s_in[ci * ROWS * WS];
      const float* swc = &s_w[ci * 288 + co0];
      for (int k = 0; k < 9; k++) {
        int ky = k / 3, kx = k % 3;
        const float4 wa = *(const float4*)&swc[k * 32];
        const float4 wb = *(const float4*)&swc[k * 32 + 4];
#pragma unroll
        for (int i = 0; i < RPT; i++) {
          float iv = sci[(2 * (s + SL * i) + ky) * WS + 2 * x + kx];
          acc[i][0] = fmaf(iv, wa.x, acc[i][0]);
          acc[i][1] = fmaf(iv, wa.y, acc[i][1]);
          acc[i][2] = fmaf(iv, wa.z, acc[i][2]);
          acc[i][3] = fmaf(iv, wa.w, acc[i][3]);
          acc[i][4] = fmaf(iv, wb.x, acc[i][4]);
          acc[i][5] = fmaf(iv, wb.y, acc[i][5]);
          acc[i][6] = fmaf(iv, wb.z, acc[i][6]);
          acc[i][7] = fmaf(iv, wb.w, acc[i][7]);
        }
      }
    }
  }

  float sm[8], sq[8];
#pragma unroll
  for (int c = 0; c < 8; c++) { sm[c] = 0.f; sq[c] = 0.f; }
#pragma unroll
  for (int i = 0; i < RPT; i++) {
    int gy = y0 + s + SL * i;
#pragma unroll
    for (int c = 0; c < 8; c++) {
      int co = co0 + c;
      float v = acc[i][c] + bias[co];
      size_t idx = (((size_t)b * 32 + co) * WO + gy) * WO + x;
      out[idx] = v;
      sm[c] += v;
      sq[c] += v * v;
    }
  }
  if (ostats) {
#pragma unroll
    for (int c = 0; c < 8; c++) {
      float a = sm[c], q = sq[c];
      for (int off = 32; off > 0; off >>= 1) {
        a += __shfl_down(a, off);
        q += __shfl_down(q, off);
      }
      if (lane == 0) {
        atomicAdd(&ostats[b * 32 + co0 + c].x, a);
        atomicAdd(&ostats[b * 32 + co0 + c].y, q);
      }
    }
  }
}

// ---------------- 7x7 s2 conv, 3->32, fused instnorm (no relu) ----------
__global__ __launch_bounds__(256) void conv7_s2(
    const float* __restrict__ in, const float2* __restrict__ statsX,
    const float* __restrict__ wT, const float* __restrict__ bias,
    float* __restrict__ out, float2* __restrict__ ostats) {
  constexpr int ROWS = 21, WS = 134;
  __shared__ float s_in[3 * ROWS * WS];
  __shared__ __align__(16) float s_w[3 * 49 * 32];
  __shared__ float2 s_ms[3];
  const int t = threadIdx.x;
  const int b = blockIdx.z;
  const int y0 = blockIdx.x * 8;
  const int x0 = blockIdx.y * 64;
  const int lane = t & 63, wv = t >> 6;
  const int co0 = wv * 8;

  if (t < 3) {
    float2 r = statsX[b * 3 + t];
    float mean = r.x * (1.f / 65536.f);
    float var = r.y * (1.f / 65536.f) - mean * mean;
    s_ms[t] = make_float2(mean, rsqrtf(var + INORM_EPS));
  }
  __syncthreads();
  for (int d = t; d < 3 * 49 * 32; d += 256) s_w[d] = wT[d];
  for (int d = t; d < 3 * ROWS * WS; d += 256) {
    int ci = d / (ROWS * WS);
    int r = d % (ROWS * WS);
    int lr = r / WS, cc = r % WS;
    int gy = 2 * y0 - 3 + lr, gx = 2 * x0 - 3 + cc;
    float v = 0.f;
    if ((unsigned)gy < 256u && (unsigned)gx < 256u) {
      float2 ms = s_ms[ci];
      v = (in[(((size_t)b * 3 + ci) * 256 + gy) * 256 + gx] - ms.x) * ms.y;
    }
    s_in[d] = v;
  }
  __syncthreads();

  float acc[8][8];
#pragma unroll
  for (int i = 0; i < 8; i++)
#pragma unroll
    for (int c = 0; c < 8; c++) acc[i][c] = 0.f;

  for (int ci = 0; ci < 3; ci++) {
    const float* sci = &s_in[ci * ROWS * WS];
    const float* swc = &s_w[ci * 49 * 32 + co0];
    for (int kx = 0; kx < 7; kx++) {
      float ivv[21];
#pragma unroll
      for (int v = 0; v < 21; v++) ivv[v] = sci[v * WS + 2 * lane + kx];
#pragma unroll
      for (int ky = 0; ky < 7; ky++) {
        const float4 wa = *(const float4*)&swc[(ky * 7 + kx) * 32];
        const float4 wb = *(const float4*)&swc[(ky * 7 + kx) * 32 + 4];
#pragma unroll
        for (int i = 0; i < 8; i++) {
          float iv = ivv[2 * i + ky];
          acc[i][0] = fmaf(iv, wa.x, acc[i][0]);
          acc[i][1] = fmaf(iv, wa.y, acc[i][1]);
          acc[i][2] = fmaf(iv, wa.z, acc[i][2]);
          acc[i][3] = fmaf(iv, wa.w, acc[i][3]);
          acc[i][4] = fmaf(iv, wb.x, acc[i][4]);
          acc[i][5] = fmaf(iv, wb.y, acc[i][5]);
          acc[i][6] = fmaf(iv, wb.z, acc[i][6]);
          acc[i][7] = fmaf(iv, wb.w, acc[i][7]);
        }
      }
    }
  }

  float sm[8], sq[8];
#pragma unroll
  for (int c = 0; c < 8; c++) { sm[c] = 0.f; sq[c] = 0.f; }
#pragma unroll
  for (int i = 0; i < 8; i++) {
    int gy = y0 + i;
#pragma unroll
    for (int c = 0; c < 8; c++) {
      int co = co0 + c;
      float v = acc[i][c] + bias[co];
      out[(((size_t)b * 32 + co) * 128 + gy) * 128 + x0 + lane] = v;
      sm[c] += v;
      sq[c] += v * v;
    }
  }
#pragma unroll
  for (int c = 0; c < 8; c++) {
    float a = sm[c], q = sq[c];
    for (int off = 32; off > 0; off >>= 1) {
      a += __shfl_down(a, off);
      q += __shfl_down(q, off);
    }
    if (lane == 0) {
      atomicAdd(&ostats[b * 32 + co0 + c].x, a);
      atomicAdd(&ostats[b * 32 + co0 + c].y, q);
    }
  }
}

// ---------------- 1x1 stride-2 skip projection, accumulate + stats ------
__global__ __launch_bounds__(256) void conv1x1_s2(
    const float* __restrict__ in, int Hin, int Win,
    const float* __restrict__ w, const float* __restrict__ bs,
    float* __restrict__ out, int Hout, int Wout, float2* __restrict__ ostats) {
  size_t idx = (size_t)blockIdx.x * 256 + threadIdx.x;
  int ox = idx % Wout;
  size_t r = idx / Wout;
  int oy = r % Hout;
  r /= Hout;
  int co = r & 31;
  int b = r >> 5;
  const float* ip = in + (((size_t)b * 32) * Hin + oy * 2) * Win + ox * 2;
  const float* wp = w + co * 32;
  float acc = bs[co];
#pragma unroll 8
  for (int ci = 0; ci < 32; ci++) acc += wp[ci] * ip[(size_t)ci * Hin * Win];
  float v = out[idx] + acc;
  out[idx] = v;
  if (ostats) {
    float a = v, q = v * v;
    for (int off = 32; off > 0; off >>= 1) {
      a += __shfl_down(a, off);
      q += __shfl_down(q, off);
    }
    if ((threadIdx.x & 63) == 0) {
      atomicAdd(&ostats[b * 32 + co].x, a);
      atomicAdd(&ostats[b * 32 + co].y, q);
    }
  }
}

// ---------------- fused attention tail ----------------------------------
__global__ __launch_bounds__(256) void attention_kernel(
    const float* __restrict__ feat, const float* __restrict__ text,
    const float* __restrict__ attn_w, const float* __restrict__ attn_b,
    const float* __restrict__ final_w, const float* __restrict__ final_b,
    float* __restrict__ out) {
  __shared__ float s_text[256];
  __shared__ float s_feat[32 * 256];
  __shared__ float s_gate[5 * 256];
  __shared__ float s_scores[5 * 32];
  __shared__ float s_probs[5 * 32];
  __shared__ float s_amap[5 * 256];
  const int b = blockIdx.x;
  const int t = threadIdx.x;

  s_text[t] = text[b * 256 + t];
  for (int i = t; i < 32 * 256; i += 256) s_feat[i] = feat[(size_t)b * 8192 + i];
  __syncthreads();

  for (int h = 0; h < 5; h++) {
    const float* wrow = attn_w + ((size_t)h * 256 + t) * 256;
    float acc = attn_b[h * 256 + t];
    for (int k = 0; k < 256; k++) acc += s_text[k] * wrow[k];
    s_gate[h * 256 + t] = 1.f / (1.f + __expf(-acc));
  }
  __syncthreads();

  if (t < 160) {
    int h = t >> 5, c = t & 31;
    float acc = 0.f;
    for (int ij = 0; ij < 256; ij++) acc += s_gate[h * 256 + ij] * s_feat[c * 256 + ij];
    s_scores[t] = acc;
  }
  __syncthreads();

  if (t < 5) {
    float mx = -1e30f;
    for (int c = 0; c < 32; c++) mx = fmaxf(mx, s_scores[t * 32 + c]);
    float sum = 0.f;
    for (int c = 0; c < 32; c++) {
      float e = __expf(s_scores[t * 32 + c] - mx);
      s_probs[t * 32 + c] = e;
      sum += e;
    }
    float inv = 1.f / sum;
    for (int c = 0; c < 32; c++) s_probs[t * 32 + c] *= inv;
  }
  __syncthreads();

  for (int h = 0; h < 5; h++) {
    float acc = 0.f;
    for (int c = 0; c < 32; c++) acc += s_probs[h * 32 + c] * s_feat[c * 256 + t];
    s_amap[h * 256 + t] = acc;
  }
  __syncthreads();

  for (int e = t; e < 512; e += 256) {
    const float* wrow = final_w + (size_t)e * 1280;
    float acc = final_b[e];
    for (int k = 0; k < 1280; k++) acc += s_amap[k] * wrow[k];
    out[(size_t)b * 512 + e] = acc;
  }
}

// -------------------------------------------------------------------------
extern "C" void kernel_launch(void* const* d_in, const int* in_sizes, int n_in,
                              void* d_out, int out_size, void* d_ws, size_t ws_size,
                              hipStream_t stream) {
  (void)in_sizes; (void)n_in; (void)out_size; (void)ws_size;
  const float* x       = (const float*)d_in[0];
  const float* text    = (const float*)d_in[1];
  const float* conv1_w = (const float*)d_in[2];
  const float* conv1_b = (const float*)d_in[3];
  const float* rbs_w1  = (const float*)d_in[4];
  const float* rbs_b1  = (const float*)d_in[5];
  const float* rbs_w2  = (const float*)d_in[6];
  const float* rbs_b2  = (const float*)d_in[7];
  const float* rbs_ws  = (const float*)d_in[8];
  const float* rbs_bs  = (const float*)d_in[9];
  const float* rb_w1   = (const float*)d_in[10];
  const float* rb_b1   = (const float*)d_in[11];
  const float* rb_w2   = (const float*)d_in[12];
  const float* rb_b2   = (const float*)d_in[13];
  const float* attn_w  = (const float*)d_in[14];
  const float* attn_b  = (const float*)d_in[15];
  const float* final_w = (const float*)d_in[16];
  const float* final_b = (const float*)d_in[17];
  float* out = (float*)d_out;

  char* wsb = (char*)d_ws;
  float* A  = (float*)wsb;                       // 64*32*128*128 = 134217728 B
  float* Bu = (float*)(wsb + 134217728);         // 33554432 B
  float* Cu = (float*)(wsb + 167772160);         // 33554432 B
  float* D  = A;                                 // alias: A dead when D written
  float2* statsX = (float2*)(wsb + 201326592);   // 192 float2
  float2* SP     = (float2*)(wsb + 201328128);   // 10 * 2048 float2
  float*  wt     = (float*)(wsb + 201491968);    // 96864 floats
  float2* SP0 = SP + 0 * 2048;
  float2* SP1 = SP + 1 * 2048;
  float2* SP2 = SP + 2 * 2048;
  float2* SP3 = SP + 3 * 2048;
  float2* SP4 = SP + 4 * 2048;
  float2* SP5 = SP + 5 * 2048;
  float2* SP6 = SP + 6 * 2048;
  float2* SP7 = SP + 7 * 2048;
  float2* SP8 = SP + 8 * 2048;
  float2* SP9 = SP + 9 * 2048;
  float* wT7    = wt;                 // 4704
  float* wTrbs1 = wt + 4704;          // 3 * 9216
  float* wTrbs2 = wt + 4704 + 27648;  // 3 * 9216
  float* wTrb1  = wt + 4704 + 55296;  // 2 * 9216
  float* wTrb2  = wt + 4704 + 73728;  // 2 * 9216

  // prep: zero stats pool, transpose weights, input stats
  zero_f2<<<80, 256, 0, stream>>>(SP, 10 * 2048);
  transpose_w3<<<108, 256, 0, stream>>>(rbs_w1, wTrbs1, 3);
  transpose_w3<<<108, 256, 0, stream>>>(rbs_w2, wTrbs2, 3);
  transpose_w3<<<72, 256, 0, stream>>>(rb_w1, wTrb1, 2);
  transpose_w3<<<72, 256, 0, stream>>>(rb_w2, wTrb2, 2);
  transpose_w7<<<19, 256, 0, stream>>>(conv1_w, wT7);
  stats_raw<<<192, 256, 0, stream>>>(x, statsX, 65536);

  // conv1: 3ch 256^2 -> 32ch 128^2
  conv7_s2<<<dim3(16, 2, 64), 256, 0, stream>>>(x, statsX, wT7, conv1_b, A, SP0);

  // rbs0: A(128^2) -> Bu(64^2) -> Cu; 1x1(A) += Cu
  conv3x3_s2<64, 1, 4><<<dim3(16, 1, 64), 256, 0, stream>>>(
      A, SP0, 1.f / 16384.f, wTrbs1, rbs_b1, Bu, SP1);
  conv3x3_s1<64, 1, 8><<<dim3(8, 1, 64), 256, 0, stream>>>(
      Bu, SP1, 1.f / 4096.f, wTrbs2, rbs_b2, nullptr, Cu, nullptr);
  conv1x1_s2<<<32768, 256, 0, stream>>>(A, 128, 128, rbs_ws, rbs_bs, Cu, 64, 64, SP2);

  // rb0: Cu -> Bu -> D (+Cu identity)
  conv3x3_s1<64, 1, 8><<<dim3(8, 1, 64), 256, 0, stream>>>(
      Cu, SP2, 1.f / 4096.f, wTrb1, rb_b1, nullptr, Bu, SP3);
  conv3x3_s1<64, 1, 8><<<dim3(8, 1, 64), 256, 0, stream>>>(
      Bu, SP3, 1.f / 4096.f, wTrb2, rb_b2, Cu, D, SP4);

  // rbs1: D(64^2) -> Bu(32^2) -> Cu; 1x1(D) += Cu
  conv3x3_s2<32, 2, 2><<<dim3(8, 1, 64), 256, 0, stream>>>(
      D, SP4, 1.f / 4096.f, wTrbs1 + 9216, rbs_b1 + 32, Bu, SP5);
  conv3x3_s1<32, 2, 4><<<dim3(4, 1, 64), 256, 0, stream>>>(
      Bu, SP5, 1.f / 1024.f, wTrbs2 + 9216, rbs_b2 + 32, nullptr, Cu, nullptr);
  conv1x1_s2<<<8192, 256, 0, stream>>>(D, 64, 64, rbs_ws + 1024, rbs_bs + 32,
                                       Cu, 32, 32, SP6);

  // rb1: Cu -> Bu -> D (+Cu identity)
  conv3x3_s1<32, 2, 4><<<dim3(4, 1, 64), 256, 0, stream>>>(
      Cu, SP6, 1.f / 1024.f, wTrb1 + 9216, rb_b1 + 32, nullptr, Bu, SP7);
  conv3x3_s1<32, 2, 4><<<dim3(4, 1, 64), 256, 0, stream>>>(
      Bu, SP7, 1.f / 1024.f, wTrb2 + 9216, rb_b2 + 32, Cu, D, SP8);

  // rbs2: D(32^2) -> Bu(16^2) -> Cu; 1x1(D) += Cu
  conv3x3_s2<16, 4, 4><<<dim3(1, 1, 64), 256, 0, stream>>>(
      D, SP8, 1.f / 1024.f, wTrbs1 + 18432, rbs_b1 + 64, Bu, SP9);
  conv3x3_s1<16, 4, 4><<<dim3(1, 1, 64), 256, 0, stream>>>(
      Bu, SP9, 1.f / 256.f, wTrbs2 + 18432, rbs_b2 + 64, nullptr, Cu, nullptr);
  conv1x1_s2<<<2048, 256, 0, stream>>>(D, 32, 32, rbs_ws + 2048, rbs_bs + 64,
                                       Cu, 16, 16, nullptr);

  // attention tail
  attention_kernel<<<64, 256, 0, stream>>>(
      Cu, text, attn_w, attn_b, final_w, final_b, out);
}

// Round 3
// 627.837 us; speedup vs baseline: 2.8167x; 2.3825x over previous
//
#include <hip/hip_runtime.h>
#include <cstdint>
#include <cstddef>

#define INORM_EPS 1e-5f

typedef _Float16 f16;
typedef f16 f16x8 __attribute__((ext_vector_type(8)));
typedef f16 f16x4 __attribute__((ext_vector_type(4)));
typedef float f32x4 __attribute__((ext_vector_type(4)));

// ---------------- zero stats pool ----------------------------------------
__global__ __launch_bounds__(256) void zero_f2(float2* __restrict__ p, int n) {
  int i = blockIdx.x * 256 + threadIdx.x;
  if (i < n) p[i] = make_float2(0.f, 0.f);
}

// ---- pack 3x3 weights: [co][ci][3][3] fp32 -> [9][2][64][8] f16 frags ----
// B-frag: lane l holds co = f*16+(l&15), k(ci) = (l>>4)*8+j
__global__ __launch_bounds__(256) void pack_w3(const float* __restrict__ src,
                                               f16* __restrict__ dst, int nmat) {
  int d = blockIdx.x * 256 + threadIdx.x;
  if (d >= nmat * 9216) return;
  int mat = d / 9216, r = d % 9216;
  int p = r >> 10;            // 0..8 (ky*3+kx)
  int f = (r >> 9) & 1;
  int l = (r >> 3) & 63;
  int j = r & 7;
  int co = f * 16 + (l & 15);
  int ci = (l >> 4) * 8 + j;
  dst[d] = (f16)src[mat * 9216 + co * 288 + ci * 9 + p];
}

// ---- pack 1x1 weights: [co][ci] -> [2][64][8] f16 ------------------------
__global__ __launch_bounds__(256) void pack_w1(const float* __restrict__ src,
                                               f16* __restrict__ dst, int nmat) {
  int d = blockIdx.x * 256 + threadIdx.x;
  if (d >= nmat * 1024) return;
  int mat = d / 1024, r = d % 1024;
  int f = r >> 9, l = (r >> 3) & 63, j = r & 7;
  dst[d] = (f16)src[mat * 1024 + (f * 16 + (l & 15)) * 32 + (l >> 4) * 8 + j];
}

// ---- pack 7x7 conv1 weights: [co][3][7][7] -> [7 ky][2][64][8] f16 -------
// k = (l>>4)*8+j; kx = k>>2 (0..7), ci = k&3; pad kx==7 or ci==3 with 0
__global__ __launch_bounds__(256) void pack_w7(const float* __restrict__ src,
                                               f16* __restrict__ dst) {
  int d = blockIdx.x * 256 + threadIdx.x;
  if (d >= 7168) return;
  int ky = d >> 10;
  int f = (d >> 9) & 1;
  int l = (d >> 3) & 63;
  int j = d & 7;
  int k = (l >> 4) * 8 + j;
  int kx = k >> 2, ci = k & 3;
  float v = 0.f;
  if (kx < 7 && ci < 3) v = src[(f * 16 + (l & 15)) * 147 + ci * 49 + ky * 7 + kx];
  dst[d] = (f16)v;
}

// ---------------- raw (sum, sumsq) stats for fp32 input x -----------------
__global__ __launch_bounds__(256) void stats_raw(const float* __restrict__ in,
                                                 float2* __restrict__ st, int HW) {
  const float4* p = (const float4*)(in + (size_t)blockIdx.x * HW);
  float s = 0.f, ss = 0.f;
  int n4 = HW >> 2;
  for (int i = threadIdx.x; i < n4; i += 256) {
    float4 v = p[i];
    s += v.x + v.y + v.z + v.w;
    ss += v.x * v.x + v.y * v.y + v.z * v.z + v.w * v.w;
  }
  __shared__ float r0[256], r1[256];
  r0[threadIdx.x] = s;
  r1[threadIdx.x] = ss;
  __syncthreads();
  for (int off = 128; off > 0; off >>= 1) {
    if ((int)threadIdx.x < off) {
      r0[threadIdx.x] += r0[threadIdx.x + off];
      r1[threadIdx.x] += r1[threadIdx.x + off];
    }
    __syncthreads();
  }
  if (threadIdx.x == 0) st[blockIdx.x] = make_float2(r0[0], r1[0]);
}

// ---- pack x: fp32 NCHW [64][3][256][256] -> normed padded f16 [64][262][262][4]
__global__ __launch_bounds__(256) void packx(const float* __restrict__ x,
                                             const float2* __restrict__ SPx,
                                             f16* __restrict__ xP) {
  int u = blockIdx.x * 256 + threadIdx.x;
  if (u >= 262 * 262) return;
  int b = blockIdx.z;
  int r = u / 262, c = u % 262;
  f16x4 out;
  out[0] = (f16)0; out[1] = (f16)0; out[2] = (f16)0; out[3] = (f16)0;
  if (r >= 3 && r < 259 && c >= 3 && c < 259) {
    int ir = r - 3, ic = c - 3;
#pragma unroll
    for (int ci = 0; ci < 3; ci++) {
      float2 s = SPx[b * 3 + ci];
      float mean = s.x * (1.f / 65536.f);
      float rstd = rsqrtf(s.y * (1.f / 65536.f) - mean * mean + INORM_EPS);
      out[ci] = (f16)((x[((size_t)b * 3 + ci) * 65536 + ir * 256 + ic] - mean) * rstd);
    }
  }
  *(f16x4*)(xP + ((size_t)b * 68644 + u) * 4) = out;
}

// ---- pack map: raw f16 NHWC W^2*32 + stats -> relu(norm) padded (W+2)^2*32
__global__ __launch_bounds__(256) void packmap(const f16* __restrict__ R,
                                               const float2* __restrict__ SP,
                                               float inv_hw, f16* __restrict__ P,
                                               int W) {
  int Wp = W + 2;
  int units = Wp * Wp * 4;
  int u = blockIdx.x * 256 + threadIdx.x;
  if (u >= units) return;
  int b = blockIdx.z;
  int c8 = u & 3, pp = u >> 2;
  int r = pp / Wp, c = pp % Wp;
  f16x8 vout;
#pragma unroll
  for (int i = 0; i < 8; i++) vout[i] = (f16)0;
  if (r >= 1 && r <= W && c >= 1 && c <= W) {
    f16x8 vin = *(const f16x8*)(R + (((size_t)b * W * W + (size_t)(r - 1) * W + (c - 1)) * 32 + c8 * 8));
#pragma unroll
    for (int i = 0; i < 8; i++) {
      float2 s = SP[b * 32 + c8 * 8 + i];
      float mean = s.x * inv_hw;
      float rstd = rsqrtf(s.y * inv_hw - mean * mean + INORM_EPS);
      float v = ((float)vin[i] - mean) * rstd;
      vout[i] = (f16)fmaxf(v, 0.f);
    }
  }
  *(f16x8*)(P + (((size_t)b * Wp * Wp + pp) * 32 + c8 * 8)) = vout;
}

// ---------------- MFMA 3x3 conv (+fused skip), f16 NHWC -------------------
// SKIP: 0 none, 1 identity add, 2 fused 1x1 stride-2 projection
template <int WIN, int STRIDE, int SKIP>
__global__ __launch_bounds__(256) void conv3(
    const f16* __restrict__ P,       // padded normed input (WIN+2)^2*32 / b
    const f16* __restrict__ wp,      // [9][2][512] f16 frags
    const float* __restrict__ bias,  // [32]
    const float* __restrict__ bias2, // skip bias (SKIP2) or null
    const f16* __restrict__ skip,    // SKIP1: raw WOUT^2 map; SKIP2: raw (2*WOUT)^2 map
    const f16* __restrict__ wps,     // SKIP2: [2][512] packed 1x1 weights
    f16* __restrict__ Rout,          // raw out WOUT^2*32
    float2* __restrict__ ostats) {
  constexpr int WOUT = WIN / STRIDE;
  constexpr int Wp = WIN + 2;
  constexpr int TPR = WOUT / 16;
  constexpr int RPB = (WOUT >= 32) ? 4 : 8;
  constexpr int UNITS = TPR * RPB;
  const int t = threadIdx.x, w = t >> 6, l = t & 63;
  const int n = l & 15, q = l >> 4;
  const int b = blockIdx.z;
  const int yb = blockIdx.x * RPB;
  const f16* Pb = P + (size_t)b * (Wp * Wp * 32);

  f16x8 wf[18];
#pragma unroll
  for (int i = 0; i < 18; i++) wf[i] = *(const f16x8*)(wp + i * 512 + l * 8);
  f16x8 wsf0, wsf1;
  if (SKIP == 2) {
    wsf0 = *(const f16x8*)(wps + l * 8);
    wsf1 = *(const f16x8*)(wps + 512 + l * 8);
  }
  float b0 = bias[n], b1 = bias[16 + n];
  if (SKIP == 2) { b0 += bias2[n]; b1 += bias2[16 + n]; }

  float sm0 = 0.f, sq0 = 0.f, sm1 = 0.f, sq1 = 0.f;
  f16* ro = Rout + (size_t)b * WOUT * WOUT * 32;
  const f16* sb = skip ? skip + (size_t)b * (SKIP == 2 ? 4 : 1) * WOUT * WOUT * 32 : nullptr;

  for (int u = w; u < UNITS; u += 4) {
    int ty = u / TPR, tx = u % TPR;
    int y = yb + ty, x0 = tx * 16;
    f32x4 acc0 = {0.f, 0.f, 0.f, 0.f}, acc1 = {0.f, 0.f, 0.f, 0.f};
    f16x8 af[9];
#pragma unroll
    for (int ky = 0; ky < 3; ky++)
#pragma unroll
      for (int kx = 0; kx < 3; kx++)
        af[ky * 3 + kx] = *(const f16x8*)(
            Pb + ((size_t)(STRIDE * y + ky) * Wp + STRIDE * (x0 + n) + kx) * 32 + q * 8);
#pragma unroll
    for (int p = 0; p < 9; p++) {
      acc0 = __builtin_amdgcn_mfma_f32_16x16x32_f16(af[p], wf[2 * p], acc0, 0, 0, 0);
      acc1 = __builtin_amdgcn_mfma_f32_16x16x32_f16(af[p], wf[2 * p + 1], acc1, 0, 0, 0);
    }
    if (SKIP == 2) {
      const int Ws = 2 * WOUT;
      f16x8 as = *(const f16x8*)(sb + ((size_t)(2 * y) * Ws + 2 * (x0 + n)) * 32 + q * 8);
      acc0 = __builtin_amdgcn_mfma_f32_16x16x32_f16(as, wsf0, acc0, 0, 0, 0);
      acc1 = __builtin_amdgcn_mfma_f32_16x16x32_f16(as, wsf1, acc1, 0, 0, 0);
    }
#pragma unroll
    for (int r = 0; r < 4; r++) {
      size_t px = (size_t)y * WOUT + x0 + q * 4 + r;
      float v0 = acc0[r] + b0;
      float v1 = acc1[r] + b1;
      if (SKIP == 1) {
        v0 += (float)sb[px * 32 + n];
        v1 += (float)sb[px * 32 + 16 + n];
      }
      ro[px * 32 + n] = (f16)v0;
      ro[px * 32 + 16 + n] = (f16)v1;
      sm0 += v0; sq0 += v0 * v0;
      sm1 += v1; sq1 += v1 * v1;
    }
  }
  if (ostats) {
    sm0 += __shfl_xor(sm0, 16); sm0 += __shfl_xor(sm0, 32);
    sq0 += __shfl_xor(sq0, 16); sq0 += __shfl_xor(sq0, 32);
    sm1 += __shfl_xor(sm1, 16); sm1 += __shfl_xor(sm1, 32);
    sq1 += __shfl_xor(sq1, 16); sq1 += __shfl_xor(sq1, 32);
    if (l < 16) {
      atomicAdd(&ostats[b * 32 + n].x, sm0);
      atomicAdd(&ostats[b * 32 + n].y, sq0);
      atomicAdd(&ostats[b * 32 + 16 + n].x, sm1);
      atomicAdd(&ostats[b * 32 + 16 + n].y, sq1);
    }
  }
}

// ---------------- MFMA 7x7 s2 conv1: xP (4ch pixel) -> R128 ---------------
__global__ __launch_bounds__(256) void conv7(
    const f16* __restrict__ xP, const f16* __restrict__ wp,
    const float* __restrict__ bias, f16* __restrict__ Rout,
    float2* __restrict__ ostats) {
  const int t = threadIdx.x, w = t >> 6, l = t & 63;
  const int n = l & 15, q = l >> 4;
  const int b = blockIdx.z;
  const int yb = blockIdx.x * 2;
  const f16* Xb = xP + (size_t)b * 68644 * 4;
  f16x8 wf[14];
#pragma unroll
  for (int i = 0; i < 14; i++) wf[i] = *(const f16x8*)(wp + i * 512 + l * 8);
  float b0 = bias[n], b1 = bias[16 + n];
  float sm0 = 0.f, sq0 = 0.f, sm1 = 0.f, sq1 = 0.f;
  f16* ro = Rout + (size_t)b * 16384 * 32;

  for (int u = w; u < 16; u += 4) {
    int ty = u >> 3, tx = u & 7;
    int y = yb + ty, x0 = tx * 16;
    f32x4 acc0 = {0.f, 0.f, 0.f, 0.f}, acc1 = {0.f, 0.f, 0.f, 0.f};
    f16x8 af[7];
#pragma unroll
    for (int ky = 0; ky < 7; ky++)
      af[ky] = *(const f16x8*)(Xb + ((size_t)(2 * y + ky) * 262 + 2 * (x0 + n) + 2 * q) * 4);
#pragma unroll
    for (int ky = 0; ky < 7; ky++) {
      acc0 = __builtin_amdgcn_mfma_f32_16x16x32_f16(af[ky], wf[2 * ky], acc0, 0, 0, 0);
      acc1 = __builtin_amdgcn_mfma_f32_16x16x32_f16(af[ky], wf[2 * ky + 1], acc1, 0, 0, 0);
    }
#pragma unroll
    for (int r = 0; r < 4; r++) {
      size_t px = (size_t)y * 128 + x0 + q * 4 + r;
      float v0 = acc0[r] + b0;
      float v1 = acc1[r] + b1;
      ro[px * 32 + n] = (f16)v0;
      ro[px * 32 + 16 + n] = (f16)v1;
      sm0 += v0; sq0 += v0 * v0;
      sm1 += v1; sq1 += v1 * v1;
    }
  }
  sm0 += __shfl_xor(sm0, 16); sm0 += __shfl_xor(sm0, 32);
  sq0 += __shfl_xor(sq0, 16); sq0 += __shfl_xor(sq0, 32);
  sm1 += __shfl_xor(sm1, 16); sm1 += __shfl_xor(sm1, 32);
  sq1 += __shfl_xor(sq1, 16); sq1 += __shfl_xor(sq1, 32);
  if (l < 16) {
    atomicAdd(&ostats[b * 32 + n].x, sm0);
    atomicAdd(&ostats[b * 32 + n].y, sq0);
    atomicAdd(&ostats[b * 32 + 16 + n].x, sm1);
    atomicAdd(&ostats[b * 32 + 16 + n].y, sq1);
  }
}

// ---------------- fused attention tail (feat = raw f16 NHWC) --------------
__global__ __launch_bounds__(256) void attention_kernel(
    const f16* __restrict__ feat, const float* __restrict__ text,
    const float* __restrict__ attn_w, const float* __restrict__ attn_b,
    const float* __restrict__ final_w, const float* __restrict__ final_b,
    float* __restrict__ out) {
  __shared__ float s_text[256];
  __shared__ float s_feat[256 * 33];
  __shared__ float s_gate[5 * 256];
  __shared__ float s_scores[5 * 32];
  __shared__ float s_probs[5 * 32];
  __shared__ float s_amap[5 * 256];
  const int b = blockIdx.x;
  const int t = threadIdx.x;

  s_text[t] = text[b * 256 + t];
  for (int i = t; i < 8192; i += 256)
    s_feat[(i >> 5) * 33 + (i & 31)] = (float)feat[(size_t)b * 8192 + i];
  __syncthreads();

  for (int h = 0; h < 5; h++) {
    const float* wrow = attn_w + ((size_t)h * 256 + t) * 256;
    float acc = attn_b[h * 256 + t];
    for (int k = 0; k < 256; k++) acc += s_text[k] * wrow[k];
    s_gate[h * 256 + t] = 1.f / (1.f + __expf(-acc));
  }
  __syncthreads();

  if (t < 160) {
    int h = t >> 5, c = t & 31;
    float acc = 0.f;
    for (int ij = 0; ij < 256; ij++) acc += s_gate[h * 256 + ij] * s_feat[ij * 33 + c];
    s_scores[t] = acc;
  }
  __syncthreads();

  if (t < 5) {
    float mx = -1e30f;
    for (int c = 0; c < 32; c++) mx = fmaxf(mx, s_scores[t * 32 + c]);
    float sum = 0.f;
    for (int c = 0; c < 32; c++) {
      float e = __expf(s_scores[t * 32 + c] - mx);
      s_probs[t * 32 + c] = e;
      sum += e;
    }
    float inv = 1.f / sum;
    for (int c = 0; c < 32; c++) s_probs[t * 32 + c] *= inv;
  }
  __syncthreads();

  for (int h = 0; h < 5; h++) {
    float acc = 0.f;
    for (int c = 0; c < 32; c++) acc += s_probs[h * 32 + c] * s_feat[t * 33 + c];
    s_amap[h * 256 + t] = acc;
  }
  __syncthreads();

  for (int e = t; e < 512; e += 256) {
    const float* wrow = final_w + (size_t)e * 1280;
    float acc = final_b[e];
    for (int k = 0; k < 1280; k++) acc += s_amap[k] * wrow[k];
    out[(size_t)b * 512 + e] = acc;
  }
}

// -------------------------------------------------------------------------
extern "C" void kernel_launch(void* const* d_in, const int* in_sizes, int n_in,
                              void* d_out, int out_size, void* d_ws, size_t ws_size,
                              hipStream_t stream) {
  (void)in_sizes; (void)n_in; (void)out_size; (void)ws_size;
  const float* x       = (const float*)d_in[0];
  const float* text    = (const float*)d_in[1];
  const float* conv1_w = (const float*)d_in[2];
  const float* conv1_b = (const float*)d_in[3];
  const float* rbs_w1  = (const float*)d_in[4];
  const float* rbs_b1  = (const float*)d_in[5];
  const float* rbs_w2  = (const float*)d_in[6];
  const float* rbs_b2  = (const float*)d_in[7];
  const float* rbs_ws  = (const float*)d_in[8];
  const float* rbs_bs  = (const float*)d_in[9];
  const float* rb_w1   = (const float*)d_in[10];
  const float* rb_b1   = (const float*)d_in[11];
  const float* rb_w2   = (const float*)d_in[12];
  const float* rb_b2   = (const float*)d_in[13];
  const float* attn_w  = (const float*)d_in[14];
  const float* attn_b  = (const float*)d_in[15];
  const float* final_w = (const float*)d_in[16];
  const float* final_b = (const float*)d_in[17];
  float* out = (float*)d_out;

  char* wsb = (char*)d_ws;
  // layout (bytes)
  f16*   P128 = (f16*)(wsb + 0);              // 69,222,400 (also xP region)
  f16*   xP   = (f16*)(wsb + 0);              // 35,145,728 (dead before P128 written)
  f16*   R128 = (f16*)(wsb + 69222400);       // 67,108,864
  f16*   R64a = (f16*)(wsb + 136331264);      // 16,777,216  (a,c,d share)
  f16*   R64b = (f16*)(wsb + 153108480);      // 16,777,216
  f16*   P64  = (f16*)(wsb + 169885696);      // 17,842,176
  f16*   R32a = (f16*)(wsb + 187727872);      // 4,194,304   (a,c,d share)
  f16*   R32b = (f16*)(wsb + 191922176);      // 4,194,304
  f16*   P32  = (f16*)(wsb + 196116480);      // 4,734,976
  f16*   R16a = (f16*)(wsb + 200851456);      // 1,048,576
  f16*   R16b = (f16*)(wsb + 201900032);      // 1,048,576
  f16*   P16  = (f16*)(wsb + 202948608);      // 1,327,104
  float2* SP  = (float2*)(wsb + 204275712);   // 10*2048 float2
  float2* SPx = (float2*)(wsb + 204439552);   // 192 float2
  f16*   wp3  = (f16*)(wsb + 204441088);      // 10*9216 f16
  f16*   wp1  = (f16*)(wsb + 204625408);      // 3*1024 f16
  f16*   wp7  = (f16*)(wsb + 204631552);      // 7168 f16
  float2* SP0 = SP + 0 * 2048;
  float2* SP1 = SP + 1 * 2048;
  float2* SP2 = SP + 2 * 2048;
  float2* SP3 = SP + 3 * 2048;
  float2* SP4 = SP + 4 * 2048;
  float2* SP5 = SP + 5 * 2048;
  float2* SP6 = SP + 6 * 2048;
  float2* SP7 = SP + 7 * 2048;
  float2* SP8 = SP + 8 * 2048;
  float2* SP9 = SP + 9 * 2048;

  // prep
  zero_f2<<<81, 256, 0, stream>>>(SP, 10 * 2048 + 192);
  pack_w3<<<108, 256, 0, stream>>>(rbs_w1, wp3, 3);
  pack_w3<<<108, 256, 0, stream>>>(rbs_w2, wp3 + 3 * 9216, 3);
  pack_w3<<<72, 256, 0, stream>>>(rb_w1, wp3 + 6 * 9216, 2);
  pack_w3<<<72, 256, 0, stream>>>(rb_w2, wp3 + 8 * 9216, 2);
  pack_w1<<<12, 256, 0, stream>>>(rbs_ws, wp1, 3);
  pack_w7<<<28, 256, 0, stream>>>(conv1_w, wp7);
  stats_raw<<<192, 256, 0, stream>>>(x, SPx, 65536);
  packx<<<dim3(269, 1, 64), 256, 0, stream>>>(x, SPx, xP);

  // conv1: 7x7 s2, 3->32, 256^2 -> 128^2
  conv7<<<dim3(64, 1, 64), 256, 0, stream>>>(xP, wp7, conv1_b, R128, SP0);
  packmap<<<dim3(265, 1, 64), 256, 0, stream>>>(R128, SP0, 1.f / 16384.f, P128, 128);

  // rbs0: 128^2 -> 64^2
  conv3<128, 2, 0><<<dim3(16, 1, 64), 256, 0, stream>>>(
      P128, wp3, rbs_b1, nullptr, nullptr, nullptr, R64a, SP1);
  packmap<<<dim3(69, 1, 64), 256, 0, stream>>>(R64a, SP1, 1.f / 4096.f, P64, 64);
  conv3<64, 1, 2><<<dim3(16, 1, 64), 256, 0, stream>>>(
      P64, wp3 + 3 * 9216, rbs_b2, rbs_bs, R128, wp1, R64b, SP2);
  packmap<<<dim3(69, 1, 64), 256, 0, stream>>>(R64b, SP2, 1.f / 4096.f, P64, 64);

  // rb0: 64^2 plain resblock (identity = R64b)
  conv3<64, 1, 0><<<dim3(16, 1, 64), 256, 0, stream>>>(
      P64, wp3 + 6 * 9216, rb_b1, nullptr, nullptr, nullptr, R64a, SP3);
  packmap<<<dim3(69, 1, 64), 256, 0, stream>>>(R64a, SP3, 1.f / 4096.f, P64, 64);
  conv3<64, 1, 1><<<dim3(16, 1, 64), 256, 0, stream>>>(
      P64, wp3 + 8 * 9216, rb_b2, nullptr, R64b, nullptr, R64a, SP4);
  packmap<<<dim3(69, 1, 64), 256, 0, stream>>>(R64a, SP4, 1.f / 4096.f, P64, 64);

  // rbs1: 64^2 -> 32^2 (skip src = R64a, the rb0 output)
  conv3<64, 2, 0><<<dim3(8, 1, 64), 256, 0, stream>>>(
      P64, wp3 + 1 * 9216, rbs_b1 + 32, nullptr, nullptr, nullptr, R32a, SP5);
  packmap<<<dim3(19, 1, 64), 256, 0, stream>>>(R32a, SP5, 1.f / 1024.f, P32, 32);
  conv3<32, 1, 2><<<dim3(8, 1, 64), 256, 0, stream>>>(
      P32, wp3 + 4 * 9216, rbs_b2 + 32, rbs_bs + 32, R64a, wp1 + 1024, R32b, SP6);
  packmap<<<dim3(19, 1, 64), 256, 0, stream>>>(R32b, SP6, 1.f / 1024.f, P32, 32);

  // rb1: 32^2 plain resblock (identity = R32b)
  conv3<32, 1, 0><<<dim3(8, 1, 64), 256, 0, stream>>>(
      P32, wp3 + 7 * 9216, rb_b1 + 32, nullptr, nullptr, nullptr, R32a, SP7);
  packmap<<<dim3(19, 1, 64), 256, 0, stream>>>(R32a, SP7, 1.f / 1024.f, P32, 32);
  conv3<32, 1, 1><<<dim3(8, 1, 64), 256, 0, stream>>>(
      P32, wp3 + 9 * 9216, rb_b2 + 32, nullptr, R32b, nullptr, R32a, SP8);
  packmap<<<dim3(19, 1, 64), 256, 0, stream>>>(R32a, SP8, 1.f / 1024.f, P32, 32);

  // rbs2: 32^2 -> 16^2 (skip src = R32a, the rb1 output)
  conv3<32, 2, 0><<<dim3(2, 1, 64), 256, 0, stream>>>(
      P32, wp3 + 2 * 9216, rbs_b1 + 64, nullptr, nullptr, nullptr, R16a, SP9);
  packmap<<<dim3(6, 1, 64), 256, 0, stream>>>(R16a, SP9, 1.f / 256.f, P16, 16);
  conv3<16, 1, 2><<<dim3(2, 1, 64), 256, 0, stream>>>(
      P16, wp3 + 5 * 9216, rbs_b2 + 64, rbs_bs + 64, R32a, wp1 + 2048, R16b, nullptr);

  // attention tail
  attention_kernel<<<64, 256, 0, stream>>>(
      R16b, text, attn_w, attn_b, final_w, final_b, out);
}

// Round 4
// 543.354 us; speedup vs baseline: 3.2547x; 1.1555x over previous
//
#include <hip/hip_runtime.h>
#include <cstdint>
#include <cstddef>

#define INORM_EPS 1e-5f

typedef _Float16 f16;
typedef f16 f16x8 __attribute__((ext_vector_type(8)));
typedef f16 f16x4 __attribute__((ext_vector_type(4)));
typedef float f32x4 __attribute__((ext_vector_type(4)));

// ---------------- zero stats pool ----------------------------------------
__global__ __launch_bounds__(256) void zero_f2(float2* __restrict__ p, int n) {
  int i = blockIdx.x * 256 + threadIdx.x;
  if (i < n) p[i] = make_float2(0.f, 0.f);
}

// ---- pack 3x3 weights: [co][ci][3][3] fp32 -> [9][2][64][8] f16 frags ----
__global__ __launch_bounds__(256) void pack_w3(const float* __restrict__ src,
                                               f16* __restrict__ dst, int nmat) {
  int d = blockIdx.x * 256 + threadIdx.x;
  if (d >= nmat * 9216) return;
  int mat = d / 9216, r = d % 9216;
  int p = r >> 10;
  int f = (r >> 9) & 1;
  int l = (r >> 3) & 63;
  int j = r & 7;
  int co = f * 16 + (l & 15);
  int ci = (l >> 4) * 8 + j;
  dst[d] = (f16)src[mat * 9216 + co * 288 + ci * 9 + p];
}

// ---- pack 1x1 weights: [co][ci] -> [2][64][8] f16 ------------------------
__global__ __launch_bounds__(256) void pack_w1(const float* __restrict__ src,
                                               f16* __restrict__ dst, int nmat) {
  int d = blockIdx.x * 256 + threadIdx.x;
  if (d >= nmat * 1024) return;
  int mat = d / 1024, r = d % 1024;
  int f = r >> 9, l = (r >> 3) & 63, j = r & 7;
  dst[d] = (f16)src[mat * 1024 + (f * 16 + (l & 15)) * 32 + (l >> 4) * 8 + j];
}

// ---- pack 7x7 conv1 weights: [co][3][7][7] -> [7 ky][2][64][8] f16 -------
__global__ __launch_bounds__(256) void pack_w7(const float* __restrict__ src,
                                               f16* __restrict__ dst) {
  int d = blockIdx.x * 256 + threadIdx.x;
  if (d >= 7168) return;
  int ky = d >> 10;
  int f = (d >> 9) & 1;
  int l = (d >> 3) & 63;
  int j = d & 7;
  int k = (l >> 4) * 8 + j;
  int kx = k >> 2, ci = k & 3;
  float v = 0.f;
  if (kx < 7 && ci < 3) v = src[(f * 16 + (l & 15)) * 147 + ci * 49 + ky * 7 + kx];
  dst[d] = (f16)v;
}

// ---------------- raw (sum, sumsq) stats for fp32 input x -----------------
__global__ __launch_bounds__(256) void stats_raw(const float* __restrict__ in,
                                                 float2* __restrict__ st, int HW) {
  const float4* p = (const float4*)(in + (size_t)blockIdx.x * HW);
  float s = 0.f, ss = 0.f;
  int n4 = HW >> 2;
  for (int i = threadIdx.x; i < n4; i += 256) {
    float4 v = p[i];
    s += v.x + v.y + v.z + v.w;
    ss += v.x * v.x + v.y * v.y + v.z * v.z + v.w * v.w;
  }
  __shared__ float r0[256], r1[256];
  r0[threadIdx.x] = s;
  r1[threadIdx.x] = ss;
  __syncthreads();
  for (int off = 128; off > 0; off >>= 1) {
    if ((int)threadIdx.x < off) {
      r0[threadIdx.x] += r0[threadIdx.x + off];
      r1[threadIdx.x] += r1[threadIdx.x + off];
    }
    __syncthreads();
  }
  if (threadIdx.x == 0) st[blockIdx.x] = make_float2(r0[0], r1[0]);
}

// ---- pack x: fp32 NCHW [64][3][256][256] -> normed padded f16 [64][262][262][4]
__global__ __launch_bounds__(256) void packx(const float* __restrict__ x,
                                             const float2* __restrict__ SPx,
                                             f16* __restrict__ xP) {
  int u = blockIdx.x * 256 + threadIdx.x;
  if (u >= 262 * 262) return;
  int b = blockIdx.z;
  int r = u / 262, c = u % 262;
  f16x4 out;
  out[0] = (f16)0; out[1] = (f16)0; out[2] = (f16)0; out[3] = (f16)0;
  if (r >= 3 && r < 259 && c >= 3 && c < 259) {
    int ir = r - 3, ic = c - 3;
#pragma unroll
    for (int ci = 0; ci < 3; ci++) {
      float2 s = SPx[b * 3 + ci];
      float mean = s.x * (1.f / 65536.f);
      float rstd = rsqrtf(s.y * (1.f / 65536.f) - mean * mean + INORM_EPS);
      out[ci] = (f16)((x[((size_t)b * 3 + ci) * 65536 + ir * 256 + ic] - mean) * rstd);
    }
  }
  *(f16x4*)(xP + ((size_t)b * 68644 + u) * 4) = out;
}

// ---- pack map: raw f16 NHWC W^2*32 + stats -> relu(norm) padded (W+2)^2*32
__global__ __launch_bounds__(256) void packmap(const f16* __restrict__ R,
                                               const float2* __restrict__ SP,
                                               float inv_hw, f16* __restrict__ P,
                                               int W) {
  int Wp = W + 2;
  int units = Wp * Wp * 4;
  int u = blockIdx.x * 256 + threadIdx.x;
  if (u >= units) return;
  int b = blockIdx.z;
  int c8 = u & 3, pp = u >> 2;
  int r = pp / Wp, c = pp % Wp;
  f16x8 vout;
#pragma unroll
  for (int i = 0; i < 8; i++) vout[i] = (f16)0;
  if (r >= 1 && r <= W && c >= 1 && c <= W) {
    f16x8 vin = *(const f16x8*)(R + (((size_t)b * W * W + (size_t)(r - 1) * W + (c - 1)) * 32 + c8 * 8));
#pragma unroll
    for (int i = 0; i < 8; i++) {
      float2 s = SP[b * 32 + c8 * 8 + i];
      float mean = s.x * inv_hw;
      float rstd = rsqrtf(s.y * inv_hw - mean * mean + INORM_EPS);
      float v = ((float)vin[i] - mean) * rstd;
      vout[i] = (f16)fmaxf(v, 0.f);
    }
  }
  *(f16x8*)(P + (((size_t)b * Wp * Wp + pp) * 32 + c8 * 8)) = vout;
}

// ---------------- MFMA 3x3 conv (+fused skip), f16 NHWC -------------------
template <int WIN, int STRIDE, int SKIP>
__global__ __launch_bounds__(256) void conv3(
    const f16* __restrict__ P, const f16* __restrict__ wp,
    const float* __restrict__ bias, const float* __restrict__ bias2,
    const f16* __restrict__ skip, const f16* __restrict__ wps,
    f16* __restrict__ Rout, float2* __restrict__ ostats) {
  constexpr int WOUT = WIN / STRIDE;
  constexpr int Wp = WIN + 2;
  constexpr int TPR = WOUT / 16;
  constexpr int RPB = (WOUT >= 32) ? 4 : 8;
  constexpr int UNITS = TPR * RPB;
  const int t = threadIdx.x, w = t >> 6, l = t & 63;
  const int n = l & 15, q = l >> 4;
  const int b = blockIdx.z;
  const int yb = blockIdx.x * RPB;
  const f16* Pb = P + (size_t)b * (Wp * Wp * 32);

  f16x8 wf[18];
#pragma unroll
  for (int i = 0; i < 18; i++) wf[i] = *(const f16x8*)(wp + i * 512 + l * 8);
  f16x8 wsf0, wsf1;
  if (SKIP == 2) {
    wsf0 = *(const f16x8*)(wps + l * 8);
    wsf1 = *(const f16x8*)(wps + 512 + l * 8);
  }
  float b0 = bias[n], b1 = bias[16 + n];
  if (SKIP == 2) { b0 += bias2[n]; b1 += bias2[16 + n]; }

  float sm0 = 0.f, sq0 = 0.f, sm1 = 0.f, sq1 = 0.f;
  f16* ro = Rout + (size_t)b * WOUT * WOUT * 32;
  const f16* sb = skip ? skip + (size_t)b * (SKIP == 2 ? 4 : 1) * WOUT * WOUT * 32 : nullptr;

  for (int u = w; u < UNITS; u += 4) {
    int ty = u / TPR, tx = u % TPR;
    int y = yb + ty, x0 = tx * 16;
    f32x4 acc0 = {0.f, 0.f, 0.f, 0.f}, acc1 = {0.f, 0.f, 0.f, 0.f};
    f16x8 af[9];
#pragma unroll
    for (int ky = 0; ky < 3; ky++)
#pragma unroll
      for (int kx = 0; kx < 3; kx++)
        af[ky * 3 + kx] = *(const f16x8*)(
            Pb + ((size_t)(STRIDE * y + ky) * Wp + STRIDE * (x0 + n) + kx) * 32 + q * 8);
#pragma unroll
    for (int p = 0; p < 9; p++) {
      acc0 = __builtin_amdgcn_mfma_f32_16x16x32_f16(af[p], wf[2 * p], acc0, 0, 0, 0);
      acc1 = __builtin_amdgcn_mfma_f32_16x16x32_f16(af[p], wf[2 * p + 1], acc1, 0, 0, 0);
    }
    if (SKIP == 2) {
      const int Ws = 2 * WOUT;
      f16x8 as = *(const f16x8*)(sb + ((size_t)(2 * y) * Ws + 2 * (x0 + n)) * 32 + q * 8);
      acc0 = __builtin_amdgcn_mfma_f32_16x16x32_f16(as, wsf0, acc0, 0, 0, 0);
      acc1 = __builtin_amdgcn_mfma_f32_16x16x32_f16(as, wsf1, acc1, 0, 0, 0);
    }
#pragma unroll
    for (int r = 0; r < 4; r++) {
      size_t px = (size_t)y * WOUT + x0 + q * 4 + r;
      float v0 = acc0[r] + b0;
      float v1 = acc1[r] + b1;
      if (SKIP == 1) {
        v0 += (float)sb[px * 32 + n];
        v1 += (float)sb[px * 32 + 16 + n];
      }
      ro[px * 32 + n] = (f16)v0;
      ro[px * 32 + 16 + n] = (f16)v1;
      sm0 += v0; sq0 += v0 * v0;
      sm1 += v1; sq1 += v1 * v1;
    }
  }
  if (ostats) {
    sm0 += __shfl_xor(sm0, 16); sm0 += __shfl_xor(sm0, 32);
    sq0 += __shfl_xor(sq0, 16); sq0 += __shfl_xor(sq0, 32);
    sm1 += __shfl_xor(sm1, 16); sm1 += __shfl_xor(sm1, 32);
    sq1 += __shfl_xor(sq1, 16); sq1 += __shfl_xor(sq1, 32);
    if (l < 16) {
      atomicAdd(&ostats[b * 32 + n].x, sm0);
      atomicAdd(&ostats[b * 32 + n].y, sq0);
      atomicAdd(&ostats[b * 32 + 16 + n].x, sm1);
      atomicAdd(&ostats[b * 32 + 16 + n].y, sq1);
    }
  }
}

// ---------------- MFMA 7x7 s2 conv1: xP (4ch pixel) -> R128 ---------------
__global__ __launch_bounds__(256) void conv7(
    const f16* __restrict__ xP, const f16* __restrict__ wp,
    const float* __restrict__ bias, f16* __restrict__ Rout,
    float2* __restrict__ ostats) {
  const int t = threadIdx.x, w = t >> 6, l = t & 63;
  const int n = l & 15, q = l >> 4;
  const int b = blockIdx.z;
  const int yb = blockIdx.x * 2;
  const f16* Xb = xP + (size_t)b * 68644 * 4;
  f16x8 wf[14];
#pragma unroll
  for (int i = 0; i < 14; i++) wf[i] = *(const f16x8*)(wp + i * 512 + l * 8);
  float b0 = bias[n], b1 = bias[16 + n];
  float sm0 = 0.f, sq0 = 0.f, sm1 = 0.f, sq1 = 0.f;
  f16* ro = Rout + (size_t)b * 16384 * 32;

  for (int u = w; u < 16; u += 4) {
    int ty = u >> 3, tx = u & 7;
    int y = yb + ty, x0 = tx * 16;
    f32x4 acc0 = {0.f, 0.f, 0.f, 0.f}, acc1 = {0.f, 0.f, 0.f, 0.f};
    f16x8 af[7];
#pragma unroll
    for (int ky = 0; ky < 7; ky++)
      af[ky] = *(const f16x8*)(Xb + ((size_t)(2 * y + ky) * 262 + 2 * (x0 + n) + 2 * q) * 4);
#pragma unroll
    for (int ky = 0; ky < 7; ky++) {
      acc0 = __builtin_amdgcn_mfma_f32_16x16x32_f16(af[ky], wf[2 * ky], acc0, 0, 0, 0);
      acc1 = __builtin_amdgcn_mfma_f32_16x16x32_f16(af[ky], wf[2 * ky + 1], acc1, 0, 0, 0);
    }
#pragma unroll
    for (int r = 0; r < 4; r++) {
      size_t px = (size_t)y * 128 + x0 + q * 4 + r;
      float v0 = acc0[r] + b0;
      float v1 = acc1[r] + b1;
      ro[px * 32 + n] = (f16)v0;
      ro[px * 32 + 16 + n] = (f16)v1;
      sm0 += v0; sq0 += v0 * v0;
      sm1 += v1; sq1 += v1 * v1;
    }
  }
  sm0 += __shfl_xor(sm0, 16); sm0 += __shfl_xor(sm0, 32);
  sq0 += __shfl_xor(sq0, 16); sq0 += __shfl_xor(sq0, 32);
  sm1 += __shfl_xor(sm1, 16); sm1 += __shfl_xor(sm1, 32);
  sq1 += __shfl_xor(sq1, 16); sq1 += __shfl_xor(sq1, 32);
  if (l < 16) {
    atomicAdd(&ostats[b * 32 + n].x, sm0);
    atomicAdd(&ostats[b * 32 + n].y, sq0);
    atomicAdd(&ostats[b * 32 + 16 + n].x, sm1);
    atomicAdd(&ostats[b * 32 + 16 + n].y, sq1);
  }
}

// ---------------- tail stage 1: gates G[o][b], o in [0,1280) --------------
// block: 16 o's, 4 waves x 4 o each; lanes = b. text staged in LDS (pad 257).
__global__ __launch_bounds__(256) void gates_kernel(
    const float* __restrict__ text,    // [64][256]
    const float* __restrict__ attn_w,  // [1280][256]
    const float* __restrict__ attn_b,  // [1280]
    float* __restrict__ G) {           // [1280][64]
  __shared__ float s_text[64 * 257];
  __shared__ float s_w[16 * 256];
  const int t = threadIdx.x, wv = t >> 6, lane = t & 63;
  const int o0 = blockIdx.x * 16;
  for (int d = t; d < 16384; d += 256) {
    int b = d >> 8, k = d & 255;
    s_text[b * 257 + k] = text[d];
  }
  for (int d = t; d < 4096; d += 256) s_w[d] = attn_w[(size_t)o0 * 256 + d];
  __syncthreads();
  float acc[4];
#pragma unroll
  for (int j = 0; j < 4; j++) acc[j] = attn_b[o0 + wv * 4 + j];
  for (int k = 0; k < 256; k++) {
    float tv = s_text[lane * 257 + k];
#pragma unroll
    for (int j = 0; j < 4; j++) acc[j] = fmaf(s_w[(wv * 4 + j) * 256 + k], tv, acc[j]);
  }
#pragma unroll
  for (int j = 0; j < 4; j++) {
    int o = o0 + wv * 4 + j;
    G[o * 64 + lane] = 1.f / (1.f + __expf(-acc[j]));
  }
}

// ---------------- tail stage 2: scores -> softmax -> amapT ----------------
// one block per b. amapT[k][b] layout (k = h*256+ij) for the final GEMM.
__global__ __launch_bounds__(256) void scores_kernel(
    const f16* __restrict__ feat,   // [64][256px][32c]
    const float* __restrict__ G,    // [1280][64]
    float* __restrict__ amapT) {    // [1280][64]
  __shared__ float s_feat[256 * 33];
  __shared__ float s_gate[1280];
  __shared__ float s_scores[5 * 32];
  __shared__ float s_probs[5 * 32];
  const int b = blockIdx.x;
  const int t = threadIdx.x;

  for (int i = t; i < 8192; i += 256)
    s_feat[(i >> 5) * 33 + (i & 31)] = (float)feat[(size_t)b * 8192 + i];
  for (int i = t; i < 1280; i += 256) s_gate[i] = G[i * 64 + b];
  __syncthreads();

  if (t < 160) {
    int h = t >> 5, c = t & 31;
    float acc = 0.f;
    for (int ij = 0; ij < 256; ij++) acc += s_gate[h * 256 + ij] * s_feat[ij * 33 + c];
    s_scores[t] = acc;
  }
  __syncthreads();

  if (t < 5) {
    float mx = -1e30f;
    for (int c = 0; c < 32; c++) mx = fmaxf(mx, s_scores[t * 32 + c]);
    float sum = 0.f;
    for (int c = 0; c < 32; c++) {
      float e = __expf(s_scores[t * 32 + c] - mx);
      s_probs[t * 32 + c] = e;
      sum += e;
    }
    float inv = 1.f / sum;
    for (int c = 0; c < 32; c++) s_probs[t * 32 + c] *= inv;
  }
  __syncthreads();

  for (int h = 0; h < 5; h++) {
    float acc = 0.f;
    for (int c = 0; c < 32; c++) acc += s_probs[h * 32 + c] * s_feat[t * 33 + c];
    amapT[(h * 256 + t) * 64 + b] = acc;
  }
}

// ---------------- tail stage 3: final linear out[b][e] --------------------
// block: 8 e's (LDS-staged final_w rows), 4 waves x 2 e; lanes = b.
__global__ __launch_bounds__(256) void final_kernel(
    const float* __restrict__ amapT,    // [1280][64]
    const float* __restrict__ final_w,  // [512][1280]
    const float* __restrict__ final_b,  // [512]
    float* __restrict__ out) {          // [64][512]
  __shared__ float s_w[8 * 1280];
  const int t = threadIdx.x, wv = t >> 6, lane = t & 63;
  const int e0 = blockIdx.x * 8;
  for (int d = t; d < 10240; d += 256) s_w[d] = final_w[(size_t)e0 * 1280 + d];
  __syncthreads();
  float acc0 = final_b[e0 + wv * 2];
  float acc1 = final_b[e0 + wv * 2 + 1];
  for (int k = 0; k < 1280; k++) {
    float av = amapT[k * 64 + lane];
    acc0 = fmaf(s_w[(wv * 2) * 1280 + k], av, acc0);
    acc1 = fmaf(s_w[(wv * 2 + 1) * 1280 + k], av, acc1);
  }
  out[(size_t)lane * 512 + e0 + wv * 2] = acc0;
  out[(size_t)lane * 512 + e0 + wv * 2 + 1] = acc1;
}

// -------------------------------------------------------------------------
extern "C" void kernel_launch(void* const* d_in, const int* in_sizes, int n_in,
                              void* d_out, int out_size, void* d_ws, size_t ws_size,
                              hipStream_t stream) {
  (void)in_sizes; (void)n_in; (void)out_size; (void)ws_size;
  const float* x       = (const float*)d_in[0];
  const float* text    = (const float*)d_in[1];
  const float* conv1_w = (const float*)d_in[2];
  const float* conv1_b = (const float*)d_in[3];
  const float* rbs_w1  = (const float*)d_in[4];
  const float* rbs_b1  = (const float*)d_in[5];
  const float* rbs_w2  = (const float*)d_in[6];
  const float* rbs_b2  = (const float*)d_in[7];
  const float* rbs_ws  = (const float*)d_in[8];
  const float* rbs_bs  = (const float*)d_in[9];
  const float* rb_w1   = (const float*)d_in[10];
  const float* rb_b1   = (const float*)d_in[11];
  const float* rb_w2   = (const float*)d_in[12];
  const float* rb_b2   = (const float*)d_in[13];
  const float* attn_w  = (const float*)d_in[14];
  const float* attn_b  = (const float*)d_in[15];
  const float* final_w = (const float*)d_in[16];
  const float* final_b = (const float*)d_in[17];
  float* out = (float*)d_out;

  char* wsb = (char*)d_ws;
  f16*   P128 = (f16*)(wsb + 0);              // 69,222,400 (also xP region)
  f16*   xP   = (f16*)(wsb + 0);
  f16*   R128 = (f16*)(wsb + 69222400);       // 67,108,864 (dead after rbs0 -> tail scratch)
  f16*   R64a = (f16*)(wsb + 136331264);
  f16*   R64b = (f16*)(wsb + 153108480);
  f16*   P64  = (f16*)(wsb + 169885696);
  f16*   R32a = (f16*)(wsb + 187727872);
  f16*   R32b = (f16*)(wsb + 191922176);
  f16*   P32  = (f16*)(wsb + 196116480);
  f16*   R16a = (f16*)(wsb + 200851456);
  f16*   R16b = (f16*)(wsb + 201900032);
  f16*   P16  = (f16*)(wsb + 202948608);
  float2* SP  = (float2*)(wsb + 204275712);
  float2* SPx = (float2*)(wsb + 204439552);
  f16*   wp3  = (f16*)(wsb + 204441088);
  f16*   wp1  = (f16*)(wsb + 204625408);
  f16*   wp7  = (f16*)(wsb + 204631552);
  // tail scratch in dead R128 region:
  float* G     = (float*)(wsb + 69222400);    // 1280*64 fp32
  float* amapT = (float*)(wsb + 69550080);    // 1280*64 fp32
  float2* SP0 = SP + 0 * 2048;
  float2* SP1 = SP + 1 * 2048;
  float2* SP2 = SP + 2 * 2048;
  float2* SP3 = SP + 3 * 2048;
  float2* SP4 = SP + 4 * 2048;
  float2* SP5 = SP + 5 * 2048;
  float2* SP6 = SP + 6 * 2048;
  float2* SP7 = SP + 7 * 2048;
  float2* SP8 = SP + 8 * 2048;
  float2* SP9 = SP + 9 * 2048;

  // prep
  zero_f2<<<81, 256, 0, stream>>>(SP, 10 * 2048 + 192);
  pack_w3<<<108, 256, 0, stream>>>(rbs_w1, wp3, 3);
  pack_w3<<<108, 256, 0, stream>>>(rbs_w2, wp3 + 3 * 9216, 3);
  pack_w3<<<72, 256, 0, stream>>>(rb_w1, wp3 + 6 * 9216, 2);
  pack_w3<<<72, 256, 0, stream>>>(rb_w2, wp3 + 8 * 9216, 2);
  pack_w1<<<12, 256, 0, stream>>>(rbs_ws, wp1, 3);
  pack_w7<<<28, 256, 0, stream>>>(conv1_w, wp7);
  stats_raw<<<192, 256, 0, stream>>>(x, SPx, 65536);
  packx<<<dim3(269, 1, 64), 256, 0, stream>>>(x, SPx, xP);

  // conv1: 7x7 s2, 3->32, 256^2 -> 128^2
  conv7<<<dim3(64, 1, 64), 256, 0, stream>>>(xP, wp7, conv1_b, R128, SP0);
  packmap<<<dim3(265, 1, 64), 256, 0, stream>>>(R128, SP0, 1.f / 16384.f, P128, 128);

  // rbs0: 128^2 -> 64^2
  conv3<128, 2, 0><<<dim3(16, 1, 64), 256, 0, stream>>>(
      P128, wp3, rbs_b1, nullptr, nullptr, nullptr, R64a, SP1);
  packmap<<<dim3(69, 1, 64), 256, 0, stream>>>(R64a, SP1, 1.f / 4096.f, P64, 64);
  conv3<64, 1, 2><<<dim3(16, 1, 64), 256, 0, stream>>>(
      P64, wp3 + 3 * 9216, rbs_b2, rbs_bs, R128, wp1, R64b, SP2);
  packmap<<<dim3(69, 1, 64), 256, 0, stream>>>(R64b, SP2, 1.f / 4096.f, P64, 64);

  // rb0: 64^2 plain resblock (identity = R64b)
  conv3<64, 1, 0><<<dim3(16, 1, 64), 256, 0, stream>>>(
      P64, wp3 + 6 * 9216, rb_b1, nullptr, nullptr, nullptr, R64a, SP3);
  packmap<<<dim3(69, 1, 64), 256, 0, stream>>>(R64a, SP3, 1.f / 4096.f, P64, 64);
  conv3<64, 1, 1><<<dim3(16, 1, 64), 256, 0, stream>>>(
      P64, wp3 + 8 * 9216, rb_b2, nullptr, R64b, nullptr, R64a, SP4);
  packmap<<<dim3(69, 1, 64), 256, 0, stream>>>(R64a, SP4, 1.f / 4096.f, P64, 64);

  // rbs1: 64^2 -> 32^2 (skip src = R64a)
  conv3<64, 2, 0><<<dim3(8, 1, 64), 256, 0, stream>>>(
      P64, wp3 + 1 * 9216, rbs_b1 + 32, nullptr, nullptr, nullptr, R32a, SP5);
  packmap<<<dim3(19, 1, 64), 256, 0, stream>>>(R32a, SP5, 1.f / 1024.f, P32, 32);
  conv3<32, 1, 2><<<dim3(8, 1, 64), 256, 0, stream>>>(
      P32, wp3 + 4 * 9216, rbs_b2 + 32, rbs_bs + 32, R64a, wp1 + 1024, R32b, SP6);
  packmap<<<dim3(19, 1, 64), 256, 0, stream>>>(R32b, SP6, 1.f / 1024.f, P32, 32);

  // rb1: 32^2 plain resblock (identity = R32b)
  conv3<32, 1, 0><<<dim3(8, 1, 64), 256, 0, stream>>>(
      P32, wp3 + 7 * 9216, rb_b1 + 32, nullptr, nullptr, nullptr, R32a, SP7);
  packmap<<<dim3(19, 1, 64), 256, 0, stream>>>(R32a, SP7, 1.f / 1024.f, P32, 32);
  conv3<32, 1, 1><<<dim3(8, 1, 64), 256, 0, stream>>>(
      P32, wp3 + 9 * 9216, rb_b2 + 32, nullptr, R32b, nullptr, R32a, SP8);
  packmap<<<dim3(19, 1, 64), 256, 0, stream>>>(R32a, SP8, 1.f / 1024.f, P32, 32);

  // rbs2: 32^2 -> 16^2 (skip src = R32a)
  conv3<32, 2, 0><<<dim3(2, 1, 64), 256, 0, stream>>>(
      P32, wp3 + 2 * 9216, rbs_b1 + 64, nullptr, nullptr, nullptr, R16a, SP9);
  packmap<<<dim3(6, 1, 64), 256, 0, stream>>>(R16a, SP9, 1.f / 256.f, P16, 16);
  conv3<16, 1, 2><<<dim3(2, 1, 64), 256, 0, stream>>>(
      P16, wp3 + 5 * 9216, rbs_b2 + 64, rbs_bs + 64, R32a, wp1 + 2048, R16b, nullptr);

  // attention tail (3 stages, parallel)
  gates_kernel<<<80, 256, 0, stream>>>(text, attn_w, attn_b, G);
  scores_kernel<<<64, 256, 0, stream>>>(R16b, G, amapT);
  final_kernel<<<64, 256, 0, stream>>>(amapT, final_w, final_b, out);
}

// Round 5
// 436.719 us; speedup vs baseline: 4.0494x; 1.2442x over previous
//
#include <hip/hip_runtime.h>
#include <cstdint>
#include <cstddef>

#define INORM_EPS 1e-5f

typedef _Float16 f16;
typedef f16 f16x8 __attribute__((ext_vector_type(8)));
typedef f16 f16x4 __attribute__((ext_vector_type(4)));
typedef float f32x4 __attribute__((ext_vector_type(4)));

// ---------------- one merged prep kernel ----------------------------------
// ranges: [0,20480) zero SP pool | [..+92160) pack 3x3 wts | [..+3072) 1x1 |
//         [..+7168) conv1 7x7
__global__ __launch_bounds__(256) void prep(
    const float* __restrict__ rbs_w1, const float* __restrict__ rbs_w2,
    const float* __restrict__ rb_w1, const float* __restrict__ rb_w2,
    const float* __restrict__ rbs_ws, const float* __restrict__ conv1_w,
    float2* __restrict__ SP, f16* __restrict__ wp3, f16* __restrict__ wp1,
    f16* __restrict__ wp7) {
  int i = blockIdx.x * 256 + threadIdx.x;
  if (i < 20480) { SP[i] = make_float2(0.f, 0.f); return; }
  i -= 20480;
  if (i < 92160) {  // [mat][9 taps][2 halves][64 lanes][8] ; B-frag layout
    int mat = i / 9216, r = i % 9216;
    int p = r >> 10, f = (r >> 9) & 1, l = (r >> 3) & 63, j = r & 7;
    int co = f * 16 + (l & 15), ci = (l >> 4) * 8 + j;
    const float* src; int m;
    if (mat < 3) { src = rbs_w1; m = mat; }
    else if (mat < 6) { src = rbs_w2; m = mat - 3; }
    else if (mat < 8) { src = rb_w1; m = mat - 6; }
    else { src = rb_w2; m = mat - 8; }
    wp3[i] = (f16)src[m * 9216 + co * 288 + ci * 9 + p];
    return;
  }
  i -= 92160;
  if (i < 3072) {
    int mat = i / 1024, r = i % 1024;
    int f = r >> 9, l = (r >> 3) & 63, j = r & 7;
    wp1[i] = (f16)rbs_ws[mat * 1024 + (f * 16 + (l & 15)) * 32 + (l >> 4) * 8 + j];
    return;
  }
  i -= 3072;
  int ky = i >> 10, f = (i >> 9) & 1, l = (i >> 3) & 63, j = i & 7;
  int k = (l >> 4) * 8 + j, kx = k >> 2, ci = k & 3;
  float v = 0.f;
  if (kx < 7 && ci < 3) v = conv1_w[(f * 16 + (l & 15)) * 147 + ci * 49 + ky * 7 + kx];
  wp7[i] = (f16)v;
}

// ---------------- raw (sum, sumsq) stats for fp32 input x -----------------
__global__ __launch_bounds__(256) void stats_raw(const float* __restrict__ in,
                                                 float2* __restrict__ st, int HW) {
  const float4* p = (const float4*)(in + (size_t)blockIdx.x * HW);
  float s = 0.f, ss = 0.f;
  int n4 = HW >> 2;
  for (int i = threadIdx.x; i < n4; i += 256) {
    float4 v = p[i];
    s += v.x + v.y + v.z + v.w;
    ss += v.x * v.x + v.y * v.y + v.z * v.z + v.w * v.w;
  }
  __shared__ float r0[256], r1[256];
  r0[threadIdx.x] = s;
  r1[threadIdx.x] = ss;
  __syncthreads();
  for (int off = 128; off > 0; off >>= 1) {
    if ((int)threadIdx.x < off) {
      r0[threadIdx.x] += r0[threadIdx.x + off];
      r1[threadIdx.x] += r1[threadIdx.x + off];
    }
    __syncthreads();
  }
  if (threadIdx.x == 0) st[blockIdx.x] = make_float2(r0[0], r1[0]);
}

// ---- pack x: fp32 NCHW [64][3][256][256] -> normed padded f16 [64][262][262][4]
__global__ __launch_bounds__(256) void packx(const float* __restrict__ x,
                                             const float2* __restrict__ SPx,
                                             f16* __restrict__ xP) {
  int u = blockIdx.x * 256 + threadIdx.x;
  if (u >= 262 * 262) return;
  int b = blockIdx.z;
  int r = u / 262, c = u % 262;
  f16x4 out;
  out[0] = (f16)0; out[1] = (f16)0; out[2] = (f16)0; out[3] = (f16)0;
  if (r >= 3 && r < 259 && c >= 3 && c < 259) {
    int ir = r - 3, ic = c - 3;
#pragma unroll
    for (int ci = 0; ci < 3; ci++) {
      float2 s = SPx[b * 3 + ci];
      float mean = s.x * (1.f / 65536.f);
      float rstd = rsqrtf(s.y * (1.f / 65536.f) - mean * mean + INORM_EPS);
      out[ci] = (f16)((x[((size_t)b * 3 + ci) * 65536 + ir * 256 + ic] - mean) * rstd);
    }
  }
  *(f16x4*)(xP + ((size_t)b * 68644 + u) * 4) = out;
}

// ---------------- MFMA 3x3 conv, norm+relu fused into A-load --------------
// Input: RAW f16 NHWC map + fp32 raw stats. SKIP: 0 none, 1 identity add,
// 2 fused 1x1 stride-2 projection (raw input map, no norm).
template <int WIN, int STRIDE, int SKIP>
__global__ __launch_bounds__(256) void conv3n(
    const f16* __restrict__ Rin, const float2* __restrict__ SPin, float inv_hw,
    const f16* __restrict__ wp, const float* __restrict__ bias,
    const float* __restrict__ bias2, const f16* __restrict__ skip,
    const f16* __restrict__ wps, f16* __restrict__ Rout,
    float2* __restrict__ ostats) {
  constexpr int WOUT = WIN / STRIDE;
  constexpr int TPR = WOUT / 16;
  constexpr int RPB = (WOUT >= 32) ? 4 : 8;
  constexpr int UNITS = TPR * RPB;
  constexpr int U = UNITS / 4;
  const int t = threadIdx.x, w = t >> 6, l = t & 63;
  const int n = l & 15, q = l >> 4;
  const int b = blockIdx.z;
  const int yb = blockIdx.x * RPB;
  const f16* Rb = Rin + (size_t)b * WIN * WIN * 32;

  // per-lane A-channel (q*8+j) norm constants
  f16x8 sc, sh;
#pragma unroll
  for (int j = 0; j < 8; j++) {
    float2 s = SPin[b * 32 + q * 8 + j];
    float mean = s.x * inv_hw;
    float rstd = rsqrtf(s.y * inv_hw - mean * mean + INORM_EPS);
    sc[j] = (f16)rstd;
    sh[j] = (f16)(-mean * rstd);
  }

  f16x8 wf[18];
#pragma unroll
  for (int i = 0; i < 18; i++) wf[i] = *(const f16x8*)(wp + i * 512 + l * 8);
  f16x8 wsf0, wsf1;
  if (SKIP == 2) {
    wsf0 = *(const f16x8*)(wps + l * 8);
    wsf1 = *(const f16x8*)(wps + 512 + l * 8);
  }
  float b0 = bias[n], b1 = bias[16 + n];
  if (SKIP == 2) { b0 += bias2[n]; b1 += bias2[16 + n]; }

  f16* ro = Rout + (size_t)b * WOUT * WOUT * 32;
  const f16* sb = skip ? skip + (size_t)b * (SKIP == 2 ? 4 : 1) * WOUT * WOUT * 32 : nullptr;

  auto load_u = [&](int u, f16x8* a) {
    int ty = u / TPR, tx = u % TPR;
    int y = yb + ty;
#pragma unroll
    for (int kx = 0; kx < 3; kx++) {
      int gx = STRIDE * ((tx << 4) + n) + kx - 1;
      int gxc = min(max(gx, 0), WIN - 1);
#pragma unroll
      for (int ky = 0; ky < 3; ky++) {
        int gy = STRIDE * y + ky - 1;
        int gyc = min(max(gy, 0), WIN - 1);
        a[ky * 3 + kx] = *(const f16x8*)(Rb + ((size_t)gyc * WIN + gxc) * 32 + q * 8);
      }
    }
  };
  auto norm_u = [&](int u, f16x8* a) {
    int ty = u / TPR, tx = u % TPR;
    int y = yb + ty;
#pragma unroll
    for (int kx = 0; kx < 3; kx++) {
      int gx = STRIDE * ((tx << 4) + n) + kx - 1;
      bool okx = (unsigned)gx < (unsigned)WIN;
#pragma unroll
      for (int ky = 0; ky < 3; ky++) {
        int gy = STRIDE * y + ky - 1;
        bool ok = okx && ((unsigned)gy < (unsigned)WIN);
        f16x8 v = a[ky * 3 + kx] * sc + sh;
#pragma unroll
        for (int e = 0; e < 8; e++) v[e] = v[e] > (f16)0 ? v[e] : (f16)0;
        f16x8 z = {};
        a[ky * 3 + kx] = ok ? v : z;
      }
    }
  };

  float sm0 = 0.f, sq0 = 0.f, sm1 = 0.f, sq1 = 0.f;
  f16x8 araw[9], anxt[9];
  load_u(w, araw);
#pragma unroll
  for (int i = 0; i < U; i++) {
    int u = w + 4 * i;
    if (i + 1 < U) load_u(u + 4, anxt);
    norm_u(u, araw);
    int ty = u / TPR, tx = u % TPR;
    int y = yb + ty, x0 = tx << 4;
    f32x4 acc0 = {0.f, 0.f, 0.f, 0.f}, acc1 = {0.f, 0.f, 0.f, 0.f};
#pragma unroll
    for (int p = 0; p < 9; p++) {
      acc0 = __builtin_amdgcn_mfma_f32_16x16x32_f16(araw[p], wf[2 * p], acc0, 0, 0, 0);
      acc1 = __builtin_amdgcn_mfma_f32_16x16x32_f16(araw[p], wf[2 * p + 1], acc1, 0, 0, 0);
    }
    if (SKIP == 2) {
      const int Ws = 2 * WOUT;
      f16x8 as = *(const f16x8*)(sb + ((size_t)(2 * y) * Ws + 2 * (x0 + n)) * 32 + q * 8);
      acc0 = __builtin_amdgcn_mfma_f32_16x16x32_f16(as, wsf0, acc0, 0, 0, 0);
      acc1 = __builtin_amdgcn_mfma_f32_16x16x32_f16(as, wsf1, acc1, 0, 0, 0);
    }
#pragma unroll
    for (int r = 0; r < 4; r++) {
      size_t px = (size_t)y * WOUT + x0 + q * 4 + r;
      float v0 = acc0[r] + b0;
      float v1 = acc1[r] + b1;
      if (SKIP == 1) {
        v0 += (float)sb[px * 32 + n];
        v1 += (float)sb[px * 32 + 16 + n];
      }
      ro[px * 32 + n] = (f16)v0;
      ro[px * 32 + 16 + n] = (f16)v1;
      sm0 += v0; sq0 += v0 * v0;
      sm1 += v1; sq1 += v1 * v1;
    }
#pragma unroll
    for (int p = 0; p < 9; p++) araw[p] = anxt[p];
  }
  if (ostats) {
    sm0 += __shfl_xor(sm0, 16); sm0 += __shfl_xor(sm0, 32);
    sq0 += __shfl_xor(sq0, 16); sq0 += __shfl_xor(sq0, 32);
    sm1 += __shfl_xor(sm1, 16); sm1 += __shfl_xor(sm1, 32);
    sq1 += __shfl_xor(sq1, 16); sq1 += __shfl_xor(sq1, 32);
    if (l < 16) {
      atomicAdd(&ostats[b * 32 + n].x, sm0);
      atomicAdd(&ostats[b * 32 + n].y, sq0);
      atomicAdd(&ostats[b * 32 + 16 + n].x, sm1);
      atomicAdd(&ostats[b * 32 + 16 + n].y, sq1);
    }
  }
}

// ---------------- MFMA 7x7 s2 conv1 (pipelined units) ---------------------
__global__ __launch_bounds__(256) void conv7(
    const f16* __restrict__ xP, const f16* __restrict__ wp,
    const float* __restrict__ bias, f16* __restrict__ Rout,
    float2* __restrict__ ostats) {
  const int t = threadIdx.x, w = t >> 6, l = t & 63;
  const int n = l & 15, q = l >> 4;
  const int b = blockIdx.z;
  const int yb = blockIdx.x * 2;
  const f16* Xb = xP + (size_t)b * 68644 * 4;
  f16x8 wf[14];
#pragma unroll
  for (int i = 0; i < 14; i++) wf[i] = *(const f16x8*)(wp + i * 512 + l * 8);
  float b0 = bias[n], b1 = bias[16 + n];
  float sm0 = 0.f, sq0 = 0.f, sm1 = 0.f, sq1 = 0.f;
  f16* ro = Rout + (size_t)b * 16384 * 32;

  auto load_u = [&](int u, f16x8* a) {
    int ty = u >> 3, tx = u & 7;
    int y = yb + ty, x0 = tx * 16;
#pragma unroll
    for (int ky = 0; ky < 7; ky++)
      a[ky] = *(const f16x8*)(Xb + ((size_t)(2 * y + ky) * 262 + 2 * (x0 + n) + 2 * q) * 4);
  };

  f16x8 araw[7], anxt[7];
  load_u(w, araw);
#pragma unroll
  for (int i = 0; i < 4; i++) {
    int u = w + 4 * i;
    if (i < 3) load_u(u + 4, anxt);
    int ty = u >> 3, tx = u & 7;
    int y = yb + ty, x0 = tx * 16;
    f32x4 acc0 = {0.f, 0.f, 0.f, 0.f}, acc1 = {0.f, 0.f, 0.f, 0.f};
#pragma unroll
    for (int ky = 0; ky < 7; ky++) {
      acc0 = __builtin_amdgcn_mfma_f32_16x16x32_f16(araw[ky], wf[2 * ky], acc0, 0, 0, 0);
      acc1 = __builtin_amdgcn_mfma_f32_16x16x32_f16(araw[ky], wf[2 * ky + 1], acc1, 0, 0, 0);
    }
#pragma unroll
    for (int r = 0; r < 4; r++) {
      size_t px = (size_t)y * 128 + x0 + q * 4 + r;
      float v0 = acc0[r] + b0;
      float v1 = acc1[r] + b1;
      ro[px * 32 + n] = (f16)v0;
      ro[px * 32 + 16 + n] = (f16)v1;
      sm0 += v0; sq0 += v0 * v0;
      sm1 += v1; sq1 += v1 * v1;
    }
#pragma unroll
    for (int ky = 0; ky < 7; ky++) araw[ky] = anxt[ky];
  }
  sm0 += __shfl_xor(sm0, 16); sm0 += __shfl_xor(sm0, 32);
  sq0 += __shfl_xor(sq0, 16); sq0 += __shfl_xor(sq0, 32);
  sm1 += __shfl_xor(sm1, 16); sm1 += __shfl_xor(sm1, 32);
  sq1 += __shfl_xor(sq1, 16); sq1 += __shfl_xor(sq1, 32);
  if (l < 16) {
    atomicAdd(&ostats[b * 32 + n].x, sm0);
    atomicAdd(&ostats[b * 32 + n].y, sq0);
    atomicAdd(&ostats[b * 32 + 16 + n].x, sm1);
    atomicAdd(&ostats[b * 32 + 16 + n].y, sq1);
  }
}

// ---------------- tail stage 1: gates G[o][b] -----------------------------
__global__ __launch_bounds__(256) void gates_kernel(
    const float* __restrict__ text, const float* __restrict__ attn_w,
    const float* __restrict__ attn_b, float* __restrict__ G) {
  __shared__ float s_text[64 * 257];
  __shared__ float s_w[16 * 256];
  const int t = threadIdx.x, wv = t >> 6, lane = t & 63;
  const int o0 = blockIdx.x * 16;
  for (int d = t; d < 16384; d += 256) {
    int b = d >> 8, k = d & 255;
    s_text[b * 257 + k] = text[d];
  }
  for (int d = t; d < 4096; d += 256) s_w[d] = attn_w[(size_t)o0 * 256 + d];
  __syncthreads();
  float acc[4];
#pragma unroll
  for (int j = 0; j < 4; j++) acc[j] = attn_b[o0 + wv * 4 + j];
  for (int k = 0; k < 256; k++) {
    float tv = s_text[lane * 257 + k];
#pragma unroll
    for (int j = 0; j < 4; j++) acc[j] = fmaf(s_w[(wv * 4 + j) * 256 + k], tv, acc[j]);
  }
#pragma unroll
  for (int j = 0; j < 4; j++) {
    int o = o0 + wv * 4 + j;
    G[o * 64 + lane] = 1.f / (1.f + __expf(-acc[j]));
  }
}

// ---------------- tail stage 2: scores -> softmax -> amapT ----------------
__global__ __launch_bounds__(256) void scores_kernel(
    const f16* __restrict__ feat, const float* __restrict__ G,
    float* __restrict__ amapT) {
  __shared__ float s_feat[256 * 33];
  __shared__ float s_gate[1280];
  __shared__ float s_scores[5 * 32];
  __shared__ float s_probs[5 * 32];
  const int b = blockIdx.x;
  const int t = threadIdx.x;

  for (int i = t; i < 8192; i += 256)
    s_feat[(i >> 5) * 33 + (i & 31)] = (float)feat[(size_t)b * 8192 + i];
  for (int i = t; i < 1280; i += 256) s_gate[i] = G[i * 64 + b];
  __syncthreads();

  if (t < 160) {
    int h = t >> 5, c = t & 31;
    float acc = 0.f;
    for (int ij = 0; ij < 256; ij++) acc += s_gate[h * 256 + ij] * s_feat[ij * 33 + c];
    s_scores[t] = acc;
  }
  __syncthreads();

  if (t < 5) {
    float mx = -1e30f;
    for (int c = 0; c < 32; c++) mx = fmaxf(mx, s_scores[t * 32 + c]);
    float sum = 0.f;
    for (int c = 0; c < 32; c++) {
      float e = __expf(s_scores[t * 32 + c] - mx);
      s_probs[t * 32 + c] = e;
      sum += e;
    }
    float inv = 1.f / sum;
    for (int c = 0; c < 32; c++) s_probs[t * 32 + c] *= inv;
  }
  __syncthreads();

  for (int h = 0; h < 5; h++) {
    float acc = 0.f;
    for (int c = 0; c < 32; c++) acc += s_probs[h * 32 + c] * s_feat[t * 33 + c];
    amapT[(h * 256 + t) * 64 + b] = acc;
  }
}

// ---------------- tail stage 3: final linear ------------------------------
__global__ __launch_bounds__(256) void final_kernel(
    const float* __restrict__ amapT, const float* __restrict__ final_w,
    const float* __restrict__ final_b, float* __restrict__ out) {
  __shared__ float s_w[8 * 1280];
  const int t = threadIdx.x, wv = t >> 6, lane = t & 63;
  const int e0 = blockIdx.x * 8;
  for (int d = t; d < 10240; d += 256) s_w[d] = final_w[(size_t)e0 * 1280 + d];
  __syncthreads();
  float acc0 = final_b[e0 + wv * 2];
  float acc1 = final_b[e0 + wv * 2 + 1];
  for (int k = 0; k < 1280; k++) {
    float av = amapT[k * 64 + lane];
    acc0 = fmaf(s_w[(wv * 2) * 1280 + k], av, acc0);
    acc1 = fmaf(s_w[(wv * 2 + 1) * 1280 + k], av, acc1);
  }
  out[(size_t)lane * 512 + e0 + wv * 2] = acc0;
  out[(size_t)lane * 512 + e0 + wv * 2 + 1] = acc1;
}

// -------------------------------------------------------------------------
extern "C" void kernel_launch(void* const* d_in, const int* in_sizes, int n_in,
                              void* d_out, int out_size, void* d_ws, size_t ws_size,
                              hipStream_t stream) {
  (void)in_sizes; (void)n_in; (void)out_size; (void)ws_size;
  const float* x       = (const float*)d_in[0];
  const float* text    = (const float*)d_in[1];
  const float* conv1_w = (const float*)d_in[2];
  const float* conv1_b = (const float*)d_in[3];
  const float* rbs_w1  = (const float*)d_in[4];
  const float* rbs_b1  = (const float*)d_in[5];
  const float* rbs_w2  = (const float*)d_in[6];
  const float* rbs_b2  = (const float*)d_in[7];
  const float* rbs_ws  = (const float*)d_in[8];
  const float* rbs_bs  = (const float*)d_in[9];
  const float* rb_w1   = (const float*)d_in[10];
  const float* rb_b1   = (const float*)d_in[11];
  const float* rb_w2   = (const float*)d_in[12];
  const float* rb_b2   = (const float*)d_in[13];
  const float* attn_w  = (const float*)d_in[14];
  const float* attn_b  = (const float*)d_in[15];
  const float* final_w = (const float*)d_in[16];
  const float* final_b = (const float*)d_in[17];
  float* out = (float*)d_out;

  char* wsb = (char*)d_ws;
  f16*   xP   = (f16*)(wsb + 0);              // 35,145,728
  f16*   R128 = (f16*)(wsb + 35145728);       // 67,108,864
  f16*   R64a = (f16*)(wsb + 102254592);      // 16,777,216
  f16*   R64b = (f16*)(wsb + 119031808);
  f16*   R64c = (f16*)(wsb + 135809024);
  f16*   R32a = (f16*)(wsb + 152586240);      // 4,194,304
  f16*   R32b = (f16*)(wsb + 156780544);
  f16*   R32c = (f16*)(wsb + 160974848);
  f16*   R16a = (f16*)(wsb + 165169152);      // 1,048,576
  f16*   R16b = (f16*)(wsb + 166217728);
  float2* SP  = (float2*)(wsb + 167266304);   // 10*2048 float2
  float2* SPx = (float2*)(wsb + 167430144);   // 192 float2
  f16*   wp3  = (f16*)(wsb + 167431680);      // 10*9216
  f16*   wp1  = (f16*)(wsb + 167616000);      // 3*1024
  f16*   wp7  = (f16*)(wsb + 167622144);      // 7168
  float* G     = (float*)(wsb + 167636480);   // 1280*64
  float* amapT = (float*)(wsb + 167964160);   // 1280*64
  float2* SP0 = SP + 0 * 2048;
  float2* SP1 = SP + 1 * 2048;
  float2* SP2 = SP + 2 * 2048;
  float2* SP3 = SP + 3 * 2048;
  float2* SP4 = SP + 4 * 2048;
  float2* SP5 = SP + 5 * 2048;
  float2* SP6 = SP + 6 * 2048;
  float2* SP7 = SP + 7 * 2048;
  float2* SP8 = SP + 8 * 2048;
  float2* SP9 = SP + 9 * 2048;

  // prep (merged) + input stats + input pack
  prep<<<480, 256, 0, stream>>>(rbs_w1, rbs_w2, rb_w1, rb_w2, rbs_ws, conv1_w,
                                SP, wp3, wp1, wp7);
  stats_raw<<<192, 256, 0, stream>>>(x, SPx, 65536);
  packx<<<dim3(269, 1, 64), 256, 0, stream>>>(x, SPx, xP);

  // conv1: 7x7 s2, 3->32, 256^2 -> 128^2
  conv7<<<dim3(64, 1, 64), 256, 0, stream>>>(xP, wp7, conv1_b, R128, SP0);

  // rbs0: 128^2 -> 64^2
  conv3n<128, 2, 0><<<dim3(16, 1, 64), 256, 0, stream>>>(
      R128, SP0, 1.f / 16384.f, wp3, rbs_b1, nullptr, nullptr, nullptr, R64a, SP1);
  conv3n<64, 1, 2><<<dim3(16, 1, 64), 256, 0, stream>>>(
      R64a, SP1, 1.f / 4096.f, wp3 + 3 * 9216, rbs_b2, rbs_bs, R128, wp1, R64b, SP2);

  // rb0: 64^2 plain resblock (identity = R64b)
  conv3n<64, 1, 0><<<dim3(16, 1, 64), 256, 0, stream>>>(
      R64b, SP2, 1.f / 4096.f, wp3 + 6 * 9216, rb_b1, nullptr, nullptr, nullptr, R64c, SP3);
  conv3n<64, 1, 1><<<dim3(16, 1, 64), 256, 0, stream>>>(
      R64c, SP3, 1.f / 4096.f, wp3 + 8 * 9216, rb_b2, nullptr, R64b, nullptr, R64a, SP4);

  // rbs1: 64^2 -> 32^2 (skip src = R64a)
  conv3n<64, 2, 0><<<dim3(8, 1, 64), 256, 0, stream>>>(
      R64a, SP4, 1.f / 4096.f, wp3 + 1 * 9216, rbs_b1 + 32, nullptr, nullptr, nullptr, R32a, SP5);
  conv3n<32, 1, 2><<<dim3(8, 1, 64), 256, 0, stream>>>(
      R32a, SP5, 1.f / 1024.f, wp3 + 4 * 9216, rbs_b2 + 32, rbs_bs + 32, R64a, wp1 + 1024, R32b, SP6);

  // rb1: 32^2 plain resblock (identity = R32b)
  conv3n<32, 1, 0><<<dim3(8, 1, 64), 256, 0, stream>>>(
      R32b, SP6, 1.f / 1024.f, wp3 + 7 * 9216, rb_b1 + 32, nullptr, nullptr, nullptr, R32c, SP7);
  conv3n<32, 1, 1><<<dim3(8, 1, 64), 256, 0, stream>>>(
      R32c, SP7, 1.f / 1024.f, wp3 + 9 * 9216, rb_b2 + 32, nullptr, R32b, nullptr, R32a, SP8);

  // rbs2: 32^2 -> 16^2 (skip src = R32a)
  conv3n<32, 2, 0><<<dim3(2, 1, 64), 256, 0, stream>>>(
      R32a, SP8, 1.f / 1024.f, wp3 + 2 * 9216, rbs_b1 + 64, nullptr, nullptr, nullptr, R16a, SP9);
  conv3n<16, 1, 2><<<dim3(2, 1, 64), 256, 0, stream>>>(
      R16a, SP9, 1.f / 256.f, wp3 + 5 * 9216, rbs_b2 + 64, rbs_bs + 64, R32a, wp1 + 2048, R16b, nullptr);

  // attention tail
  gates_kernel<<<80, 256, 0, stream>>>(text, attn_w, attn_b, G);
  scores_kernel<<<64, 256, 0, stream>>>(R16b, G, amapT);
  final_kernel<<<64, 256, 0, stream>>>(amapT, final_w, final_b, out);
}